// Round 7
// baseline (746.411 us; speedup 1.0000x reference)
//
#include <hip/hip_runtime.h>
#include <math.h>

constexpr int PB = 256;          // positions per batch
constexpr int DD = 512;          // model dim
constexpr int NB = 64;           // batch
constexpr int MROWS = NB * PB;   // 16384 rows

typedef __bf16 bf16x8 __attribute__((ext_vector_type(8)));
typedef float f32x4 __attribute__((ext_vector_type(4)));
typedef unsigned short us8 __attribute__((ext_vector_type(8)));

__device__ __forceinline__ unsigned short f2b(float f) {
  unsigned int u = __float_as_uint(f);
  u += 0x7FFFu + ((u >> 16) & 1u);        // round-to-nearest-even
  return (unsigned short)(u >> 16);
}
__device__ __forceinline__ float b2f(unsigned short h) {
  return __uint_as_float(((unsigned int)h) << 16);
}

// direct global->LDS DMA, 16B per lane; lds dest must be wave-uniform base
__device__ __forceinline__ void gload16(const void* g, const void* l) {
  __builtin_amdgcn_global_load_lds(
      (const __attribute__((address_space(1))) unsigned int*)(uintptr_t)g,
      (__attribute__((address_space(3))) unsigned int*)(unsigned int)(uintptr_t)l,
      16, 0, 0);
}

// ---------------------------------------------------------------------------
// f32 routing GEMM, REDESIGNED for occupancy: 64x64 tile, 4x4 micro, BK=16,
// register-prefetch dbuf, __launch_bounds__(256,8) to force VGPR<=64 ->
// 8 waves/SIMD (R6 was 4). Grid 4096 blocks (16/CU). fmaf chain per output
// (ascending k, bias at end) IDENTICAL to all passing rounds -> bit-exact.
// Chunked XCD swizzle: 16 col-blocks of one row-panel land on one XCD.
// ---------------------------------------------------------------------------
__global__ __launch_bounds__(256, 8) void gemm_routing(
    const float* __restrict__ x,
    const float* __restrict__ wq_r, const float* __restrict__ bq_r,
    const float* __restrict__ wk_r, const float* __restrict__ bk_r,
    float* __restrict__ S0, float* __restrict__ S1)
{
  __shared__ float As[2][16][68];
  __shared__ float Bs[2][16][68];
  const int tid = threadIdx.x;
  const int tx = tid & 15, ty = tid >> 4;

  // hw block id -> chunked XCD swizzle (4096 = 8 XCDs x 512)
  const int hw = blockIdx.y * 16 + blockIdx.x;
  const int lid = (hw & 7) * 512 + (hw >> 3);
  const int bx = lid & 15, by = lid >> 4;     // bx fastest: same row-panel
  const float* Wm   = (bx < 8) ? wq_r : wk_r;
  const float* bias = (bx < 8) ? bq_r : bk_r;
  float* C          = (bx < 8) ? S0 : S1;
  const int row0 = by * 64, col0 = (bx & 7) * 64;

  // A staging: thread t -> x row (row0 + t>>2), k chunk (t&3)*4
  const int a_r = tid >> 2, a_k4 = (tid & 3) << 2;
  const int gr = row0 + a_r;
  const unsigned aoff = (unsigned)((gr >> 8) * 257 + (gr & 255) + 1) * DD + a_k4;
  // B staging: thread t -> W row (t>>4), col chunk col0 + (t&15)*4
  const int b_k = tid >> 4, b_c4 = (tid & 15) << 2;
  const unsigned boff = (unsigned)b_k * DD + col0 + b_c4;

  float acc[4][4] = {};

  float4 pa = *(const float4*)(x + aoff);
  float4 pb = *(const float4*)(Wm + boff);

  for (int t = 0; t < 32; ++t) {
    const int buf = t & 1;
    As[buf][a_k4 + 0][a_r] = pa.x;
    As[buf][a_k4 + 1][a_r] = pa.y;
    As[buf][a_k4 + 2][a_r] = pa.z;
    As[buf][a_k4 + 3][a_r] = pa.w;
    *(float4*)&Bs[buf][b_k][b_c4] = pb;
    __syncthreads();

    if (t < 31) {                       // prefetch next K-tile under compute
      const unsigned k0 = (unsigned)(t + 1) << 4;
      pa = *(const float4*)(x + aoff + k0);
      pb = *(const float4*)(Wm + boff + k0 * DD);
    }

#pragma unroll
    for (int kk = 0; kk < 16; ++kk) {
      float4 av = *(const float4*)&As[buf][kk][ty * 4];
      float4 bv = *(const float4*)&Bs[buf][kk][tx * 4];
      float a4[4] = {av.x, av.y, av.z, av.w};
      float b4[4] = {bv.x, bv.y, bv.z, bv.w};
#pragma unroll
      for (int i = 0; i < 4; ++i)
#pragma unroll
        for (int j = 0; j < 4; ++j)
          acc[i][j] = fmaf(a4[i], b4[j], acc[i][j]);
    }
    // single barrier per K-step: next iter writes the other buffer
  }

#pragma unroll
  for (int i = 0; i < 4; ++i) {
    const int r = row0 + ty * 4 + i;
    const int c = col0 + tx * 4;
    float4 o;
    o.x = acc[i][0] + bias[c + 0];
    o.y = acc[i][1] + bias[c + 1];
    o.z = acc[i][2] + bias[c + 2];
    o.w = acc[i][3] + bias[c + 3];
    *(float4*)(C + (size_t)r * DD + c) = o;
  }
}

// ---------------------------------------------------------------------------
// Batched scores GEMM (f32, 64x64 tiles, 1024 blocks) — R2-proven
// ---------------------------------------------------------------------------
__global__ __launch_bounds__(256) void gemm_scores(
    const float* __restrict__ Q, const float* __restrict__ Kr,
    float* __restrict__ S)
{
  __shared__ float As[16][65];
  __shared__ float Bs[16][65];
  const int b = blockIdx.z;
  const int tid = threadIdx.x;
  const int tx = tid & 15, ty = tid >> 4;
  const int p0 = blockIdx.y * 64, q0 = blockIdx.x * 64;
  const float* Qb = Q + (long)b * PB * DD;
  const float* Kb = Kr + (long)b * PB * DD;
  const int a_r = tid >> 2, a_k = (tid & 3) << 2;
  const int b_n = tid & 63, b_k4 = (tid >> 6) << 2;
  float acc[4][4] = {};

  for (int k0 = 0; k0 < DD; k0 += 16) {
    float4 av = *(const float4*)(Qb + (long)(p0 + a_r) * DD + k0 + a_k);
    As[a_k + 0][a_r] = av.x;
    As[a_k + 1][a_r] = av.y;
    As[a_k + 2][a_r] = av.z;
    As[a_k + 3][a_r] = av.w;
    float4 bv = *(const float4*)(Kb + (long)(q0 + b_n) * DD + k0 + b_k4);
    Bs[b_k4 + 0][b_n] = bv.x;
    Bs[b_k4 + 1][b_n] = bv.y;
    Bs[b_k4 + 2][b_n] = bv.z;
    Bs[b_k4 + 3][b_n] = bv.w;
    __syncthreads();
#pragma unroll
    for (int kk = 0; kk < 16; ++kk) {
      float a[4], b2[4];
#pragma unroll
      for (int i = 0; i < 4; ++i) a[i] = As[kk][ty * 4 + i];
#pragma unroll
      for (int j = 0; j < 4; ++j) b2[j] = Bs[kk][tx * 4 + j];
#pragma unroll
      for (int i = 0; i < 4; ++i)
#pragma unroll
        for (int j = 0; j < 4; ++j)
          acc[i][j] = fmaf(a[i], b2[j], acc[i][j]);
    }
    __syncthreads();
  }

  float* Sb = S + (long)b * PB * PB;
#pragma unroll
  for (int i = 0; i < 4; ++i) {
    int p = p0 + ty * 4 + i;
    int q = q0 + tx * 4;
    float4 o = make_float4(acc[i][0], acc[i][1], acc[i][2], acc[i][3]);
    *(float4*)(Sb + (long)p * PB + q) = o;
  }
}

// ---------------------------------------------------------------------------
// split xp (with +1 row mapping) into bf16 hi/lo planes
// ---------------------------------------------------------------------------
__global__ __launch_bounds__(256) void split_x(
    const float* __restrict__ x, unsigned short* __restrict__ hi,
    unsigned short* __restrict__ lo)
{
  size_t i = (size_t)blockIdx.x * 256 + threadIdx.x;
  int row = (int)(i >> 6);
  int col = ((int)i & 63) << 3;
  const float* src = x + ((size_t)(row >> 8) * 257 + (row & 255) + 1) * DD + col;
  float4 a = *(const float4*)src;
  float4 b = *(const float4*)(src + 4);
  float v[8] = {a.x, a.y, a.z, a.w, b.x, b.y, b.z, b.w};
  us8 H, L;
#pragma unroll
  for (int j = 0; j < 8; ++j) {
    unsigned short h = f2b(v[j]);
    H[j] = h;
    L[j] = f2b(v[j] - b2f(h));
  }
  size_t o = (size_t)row * DD + col;
  *(us8*)(hi + o) = H;
  *(us8*)(lo + o) = L;
}

// ---------------------------------------------------------------------------
// split + TRANSPOSE a 512x512 weight into bf16 hi/lo planes: out[c][k]=W[k][c]
// ---------------------------------------------------------------------------
__global__ __launch_bounds__(256) void split_w(
    const float* __restrict__ W, unsigned short* __restrict__ hiT,
    unsigned short* __restrict__ loT)
{
  __shared__ float T[64][65];
  const int t = threadIdx.x;
  const int r0 = blockIdx.y * 64, c0 = blockIdx.x * 64;
  const int lr = t >> 2, lc4 = (t & 3) << 4;
#pragma unroll
  for (int j = 0; j < 4; ++j) {
    float4 v = *(const float4*)(W + (size_t)(r0 + lr) * DD + c0 + lc4 + j * 4);
    T[lr][lc4 + j * 4 + 0] = v.x;
    T[lr][lc4 + j * 4 + 1] = v.y;
    T[lr][lc4 + j * 4 + 2] = v.z;
    T[lr][lc4 + j * 4 + 3] = v.w;
  }
  __syncthreads();
  us8 H0, L0, H1, L1;
#pragma unroll
  for (int j = 0; j < 8; ++j) {
    float v0 = T[lc4 + j][lr];
    float v1 = T[lc4 + 8 + j][lr];
    unsigned short h0 = f2b(v0), h1 = f2b(v1);
    H0[j] = h0; L0[j] = f2b(v0 - b2f(h0));
    H1[j] = h1; L1[j] = f2b(v1 - b2f(h1));
  }
  size_t o = (size_t)(c0 + lr) * DD + r0 + lc4;
  *(us8*)(hiT + o) = H0;
  *(us8*)(hiT + o + 8) = H1;
  *(us8*)(loT + o) = L0;
  *(us8*)(loT + o + 8) = L1;
}

// ---------------------------------------------------------------------------
// bf16x3 split MFMA GEMM, MULTI-WEIGHT (R6-proven): one dispatch computes NW
// projections of the same A. Bit-identical MFMA chain per output.
// ---------------------------------------------------------------------------
template<int NW>
__global__ __launch_bounds__(256) void gemm3m(
    const unsigned short* __restrict__ Ahi, const unsigned short* __restrict__ Alo,
    const unsigned short* __restrict__ B0h, const unsigned short* __restrict__ B0l,
    const unsigned short* __restrict__ B1h, const unsigned short* __restrict__ B1l,
    const unsigned short* __restrict__ B2h, const unsigned short* __restrict__ B2l,
    const float* __restrict__ bias0, const float* __restrict__ bias1,
    const float* __restrict__ bias2,
    float* __restrict__ C0, float* __restrict__ C1, float* __restrict__ C2)
{
  __shared__ unsigned short Ah[128 * 32], Al[128 * 32];
  __shared__ unsigned short Bh[128 * 32], Bl[128 * 32];
  const int tid = threadIdx.x;
  const int wave = tid >> 6, lane = tid & 63;
  const int wr = wave >> 1, wc = wave & 1;

  const int lid = blockIdx.y * (4 * NW) + blockIdx.x;
  const int swz = (lid & 7) * (64 * NW) + (lid >> 3);
  const int wsel = swz >> 9;
  const int r9 = swz & 511;
  const int row0 = (r9 >> 2) * 128, col0 = (r9 & 3) * 128;

  const unsigned short* BhiT = (NW == 1 || wsel == 0) ? B0h : (wsel == 1) ? B1h : B2h;
  const unsigned short* BloT = (NW == 1 || wsel == 0) ? B0l : (wsel == 1) ? B1l : B2l;
  const float* bias          = (NW == 1 || wsel == 0) ? bias0 : (wsel == 1) ? bias1 : bias2;
  float* C                   = (NW == 1 || wsel == 0) ? C0 : (wsel == 1) ? C1 : C2;

  const int lr = lane & 15, lk = lane >> 4;
  f32x4 acc[4][4] = {};

  const int sr = tid >> 2;
  const int schunk = (tid & 3) ^ ((sr >> 1) & 3);
  const unsigned int lds0 = (unsigned int)wave * 512;
  const size_t ga0 = (size_t)(row0 + sr) * DD + (schunk << 3);
  const size_t ga1 = ga0 + (size_t)64 * DD;
  const size_t gb0 = (size_t)(col0 + sr) * DD + (schunk << 3);
  const size_t gb1 = gb0 + (size_t)64 * DD;

  int aoff[4], boff[4];
#pragma unroll
  for (int m = 0; m < 4; ++m) {
    int row = wr * 64 + m * 16 + lr;
    aoff[m] = row * 32 + ((lk ^ ((row >> 1) & 3)) << 3);
  }
#pragma unroll
  for (int n = 0; n < 4; ++n) {
    int row = wc * 64 + n * 16 + lr;
    boff[n] = row * 32 + ((lk ^ ((row >> 1) & 3)) << 3);
  }

  for (int k0 = 0; k0 < DD; k0 += 32) {
    gload16(Ahi + ga0 + k0, Ah + lds0);
    gload16(Ahi + ga1 + k0, Ah + lds0 + 2048);
    gload16(Alo + ga0 + k0, Al + lds0);
    gload16(Alo + ga1 + k0, Al + lds0 + 2048);
    gload16(BhiT + gb0 + k0, Bh + lds0);
    gload16(BhiT + gb1 + k0, Bh + lds0 + 2048);
    gload16(BloT + gb0 + k0, Bl + lds0);
    gload16(BloT + gb1 + k0, Bl + lds0 + 2048);
    __syncthreads();

    bf16x8 a[8], b[8];
#pragma unroll
    for (int m = 0; m < 4; ++m) {
      a[m]     = *(const bf16x8*)(Ah + aoff[m]);
      a[m + 4] = *(const bf16x8*)(Al + aoff[m]);
    }
#pragma unroll
    for (int n = 0; n < 4; ++n) {
      b[n]     = *(const bf16x8*)(Bh + boff[n]);
      b[n + 4] = *(const bf16x8*)(Bl + boff[n]);
    }
#pragma unroll
    for (int m = 0; m < 4; ++m)
#pragma unroll
      for (int n = 0; n < 4; ++n) {
        f32x4 c = acc[m][n];
        c = __builtin_amdgcn_mfma_f32_16x16x32_bf16(a[m],     b[n],     c, 0, 0, 0);
        c = __builtin_amdgcn_mfma_f32_16x16x32_bf16(a[m],     b[n + 4], c, 0, 0, 0);
        c = __builtin_amdgcn_mfma_f32_16x16x32_bf16(a[m + 4], b[n],     c, 0, 0, 0);
        acc[m][n] = c;
      }
    __syncthreads();
  }

  float bcol[4];
#pragma unroll
  for (int n = 0; n < 4; ++n) bcol[n] = bias[col0 + wc * 64 + n * 16 + lr];
#pragma unroll
  for (int m = 0; m < 4; ++m)
#pragma unroll
    for (int j = 0; j < 4; ++j) {
      int r = row0 + wr * 64 + m * 16 + lk * 4 + j;
#pragma unroll
      for (int n = 0; n < 4; ++n)
        C[(size_t)r * DD + col0 + wc * 64 + n * 16 + lr] = acc[m][n][j] + bcol[n];
    }
}

// ---------------------------------------------------------------------------
// l2norm (one dispatch over the contiguous S0|S1 region) / topk
// ---------------------------------------------------------------------------
__global__ __launch_bounds__(256) void l2norm_rows(float* __restrict__ X)
{
  const int row = blockIdx.x * 4 + (threadIdx.x >> 6);
  const int lane = threadIdx.x & 63;
  float* base = X + (long)row * DD + lane * 8;
  float4 u = *(float4*)base;
  float4 w = *(float4*)(base + 4);
  float s = u.x * u.x + u.y * u.y + u.z * u.z + u.w * u.w +
            w.x * w.x + w.y * w.y + w.z * w.z + w.w * w.w;
#pragma unroll
  for (int off = 1; off < 64; off <<= 1) s += __shfl_xor(s, off);
  float inv = 1.0f / sqrtf(s + 1e-12f);
  u.x *= inv; u.y *= inv; u.z *= inv; u.w *= inv;
  w.x *= inv; w.y *= inv; w.z *= inv; w.w *= inv;
  *(float4*)base = u;
  *(float4*)(base + 4) = w;
}

__global__ __launch_bounds__(256) void topk_routes(
    const float* __restrict__ S, const float* __restrict__ pb,
    int* __restrict__ routes)
{
  const int row = blockIdx.x * 4 + (threadIdx.x >> 6);
  const int lane = threadIdx.x & 63;
  const int p = row & 255;
  const float* srow = S + (long)row * 256;
  float v[4];
  int id[4];
#pragma unroll
  for (int i = 0; i < 4; ++i) {
    int q = i * 64 + lane;
    float s = srow[q] + pb[p * 256 + q];
    if (q == p) s = -1e9f;
    v[i] = s;
    id[i] = q;
  }
  for (int t = 0; t < 8; ++t) {
    float bv = v[0]; int bi = id[0]; int bs = 0;
#pragma unroll
    for (int i = 1; i < 4; ++i)
      if (v[i] > bv || (v[i] == bv && id[i] < bi)) { bv = v[i]; bi = id[i]; bs = i; }
    float rv = bv; int ri = bi;
#pragma unroll
    for (int off = 1; off < 64; off <<= 1) {
      float ov = __shfl_xor(rv, off);
      int oi = __shfl_xor(ri, off);
      if (ov > rv || (ov == rv && oi < ri)) { rv = ov; ri = oi; }
    }
    if (bi == ri) v[bs] = -INFINITY;
    if (lane == 0) routes[row * 8 + t] = ri;
  }
}

// ---------------------------------------------------------------------------
// Gathered 8-key attention; emits ctx as bf16 hi/lo planes for gemm3m.
// ---------------------------------------------------------------------------
__global__ __launch_bounds__(512) void wormhole_attn(
    const float* __restrict__ qh, const float* __restrict__ kh,
    const float* __restrict__ vh, const int* __restrict__ routes,
    unsigned short* __restrict__ chi, unsigned short* __restrict__ clo)
{
  const int bp = blockIdx.x;
  const int b = bp >> 8;
  const int tid = threadIdx.x;
  __shared__ int rs[8];
  if (tid < 8) rs[tid] = routes[bp * 8 + tid];
  __syncthreads();

  const float q = qh[(long)bp * DD + tid];
  long rbase[8];
  float s[8];
#pragma unroll
  for (int k = 0; k < 8; ++k) {
    long roff = ((long)((b << 8) | rs[k])) * DD + tid;
    rbase[k] = roff;
    float t = q * kh[roff];
#pragma unroll
    for (int off = 1; off < 64; off <<= 1) t += __shfl_xor(t, off);
    s[k] = t * 0.125f;
  }
  float m = s[0];
#pragma unroll
  for (int k = 1; k < 8; ++k) m = fmaxf(m, s[k]);
  float e[8], sum = 0.f;
#pragma unroll
  for (int k = 0; k < 8; ++k) { e[k] = expf(s[k] - m); sum += e[k]; }
  float inv = 1.0f / sum;
  float c = 0.f;
#pragma unroll
  for (int k = 0; k < 8; ++k) c = fmaf(e[k] * inv, vh[rbase[k]], c);
  unsigned short h = f2b(c);
  chi[(size_t)bp * DD + tid] = h;
  clo[(size_t)bp * DD + tid] = f2b(c - b2f(h));
}

// ---------------------------------------------------------------------------
extern "C" void kernel_launch(void* const* d_in, const int* in_sizes, int n_in,
                              void* d_out, int out_size, void* d_ws, size_t ws_size,
                              hipStream_t stream)
{
  const float* x        = (const float*)d_in[0];
  const float* wq_r     = (const float*)d_in[1];
  const float* bq_r     = (const float*)d_in[2];
  const float* wk_r     = (const float*)d_in[3];
  const float* bk_r     = (const float*)d_in[4];
  const float* pos_bias = (const float*)d_in[5];
  const float* wq       = (const float*)d_in[6];
  const float* bq       = (const float*)d_in[7];
  const float* wk       = (const float*)d_in[8];
  const float* bk       = (const float*)d_in[9];
  const float* wv       = (const float*)d_in[10];
  const float* bv       = (const float*)d_in[11];
  const float* wo       = (const float*)d_in[12];
  const float* bo       = (const float*)d_in[13];

  char* w = (char*)d_ws;
  const size_t SLOT = (size_t)MROWS * DD * sizeof(float);   // 33.55 MB
  unsigned short* Xhi = (unsigned short*)w;
  unsigned short* Xlo = (unsigned short*)(w + SLOT / 2);
  float* S0 = (float*)(w + SLOT);
  float* S1 = (float*)(w + 2 * SLOT);
  float* S2 = (float*)(w + 3 * SLOT);
  int* routes = (int*)(w + 4 * SLOT);
  const size_t WSZ = (size_t)DD * DD * sizeof(unsigned short);
  unsigned short* Wp = (unsigned short*)(w + 4 * SLOT + (1 << 20));
  unsigned short* Wq_hi = Wp + 0 * (WSZ / 2), *Wq_lo = Wp + 1 * (WSZ / 2);
  unsigned short* Wk_hi = Wp + 2 * (WSZ / 2), *Wk_lo = Wp + 3 * (WSZ / 2);
  unsigned short* Wv_hi = Wp + 4 * (WSZ / 2), *Wv_lo = Wp + 5 * (WSZ / 2);
  unsigned short* Wo_hi = Wp + 6 * (WSZ / 2), *Wo_lo = Wp + 7 * (WSZ / 2);

  unsigned short* Chi = Xhi;   // ctx reuses X region (X dead after vh GEMM)
  unsigned short* Clo = Xlo;

  dim3 blk(256);
  dim3 gw(8, 8);
  dim3 gr(16, 256);             // routing: 4096 blocks (64x64 tiles, 2 weights)
  dim3 gs(4, 4, 64);            // scores: 64x64 tiles x batch
  dim3 g3a(12, 128);            // gemm3m<3>: 1536 blocks
  dim3 g3b(4, 128);             // gemm3m<1>: 512 blocks

  // --- operand prep (bf16 hi/lo splits)
  split_x<<<4096, 256, 0, stream>>>(x, Xhi, Xlo);
  split_w<<<gw, 256, 0, stream>>>(wq, Wq_hi, Wq_lo);
  split_w<<<gw, 256, 0, stream>>>(wk, Wk_hi, Wk_lo);
  split_w<<<gw, 256, 0, stream>>>(wv, Wv_hi, Wv_lo);
  split_w<<<gw, 256, 0, stream>>>(wo, Wo_hi, Wo_lo);

  // --- routing path (f32; bit-identical fma order preserved)
  gemm_routing<<<gr, blk, 0, stream>>>(x, wq_r, bq_r, wk_r, bk_r, S0, S1);
  l2norm_rows<<<(2 * MROWS) / 4, 256, 0, stream>>>(S0);   // S0|S1 contiguous
  gemm_scores<<<gs, blk, 0, stream>>>(S0, S1, S2);
  topk_routes<<<MROWS / 4, 256, 0, stream>>>(S2, pos_bias, routes);

  // --- q,k,v head projections fused into ONE bf16x3 MFMA dispatch
  gemm3m<3><<<g3a, blk, 0, stream>>>(Xhi, Xlo,
      Wq_hi, Wq_lo, Wk_hi, Wk_lo, Wv_hi, Wv_lo,
      bq, bk, bv, S0, S1, S2);

  // --- gathered attention (emits ctx hi/lo) + output projection (MFMA)
  wormhole_attn<<<MROWS, 512, 0, stream>>>(S0, S1, S2, routes, Chi, Clo);
  gemm3m<1><<<g3b, blk, 0, stream>>>(Chi, Clo,
      Wo_hi, Wo_lo, Wo_hi, Wo_lo, Wo_hi, Wo_lo,
      bo, bo, bo, (float*)d_out, (float*)d_out, (float*)d_out);
}

// Round 8
// 672.252 us; speedup vs baseline: 1.1103x; 1.1103x over previous
//
#include <hip/hip_runtime.h>
#include <math.h>

constexpr int PB = 256;          // positions per batch
constexpr int DD = 512;          // model dim
constexpr int NB = 64;           // batch
constexpr int MROWS = NB * PB;   // 16384 rows

typedef __bf16 bf16x8 __attribute__((ext_vector_type(8)));
typedef float f32x4 __attribute__((ext_vector_type(4)));
typedef unsigned short us8 __attribute__((ext_vector_type(8)));

__device__ __forceinline__ unsigned short f2b(float f) {
  unsigned int u = __float_as_uint(f);
  u += 0x7FFFu + ((u >> 16) & 1u);        // round-to-nearest-even
  return (unsigned short)(u >> 16);
}
__device__ __forceinline__ float b2f(unsigned short h) {
  return __uint_as_float(((unsigned int)h) << 16);
}

// direct global->LDS DMA, 16B per lane; lds dest must be wave-uniform base
__device__ __forceinline__ void gload16(const void* g, const void* l) {
  __builtin_amdgcn_global_load_lds(
      (const __attribute__((address_space(1))) unsigned int*)(uintptr_t)g,
      (__attribute__((address_space(3))) unsigned int*)(unsigned int)(uintptr_t)l,
      16, 0, 0);
}

// ---------------------------------------------------------------------------
// MERGED f32 routing GEMM — R6 body, REVERTED byte-for-byte (measured 205 us;
// R7's occupancy-forced 64^2 variant spilled: VGPR 32, 438 MB scratch writes).
// ---------------------------------------------------------------------------
__global__ __launch_bounds__(256) void gemm_routing(
    const float* __restrict__ x,
    const float* __restrict__ wq_r, const float* __restrict__ bq_r,
    const float* __restrict__ wk_r, const float* __restrict__ bk_r,
    float* __restrict__ S0, float* __restrict__ S1)
{
  __shared__ float As[2][16][132];
  __shared__ float Bs[2][16][132];
  const int tid = threadIdx.x;
  const int tx = tid & 15, ty = tid >> 4;

  const int lid = blockIdx.x + (blockIdx.y << 3);     // gridDim.x == 8
  const int swz = (lid & 7) * 128 + (lid >> 3);
  const int bx = swz & 7, by = swz >> 3;
  const float* Wm   = (bx < 4) ? wq_r : wk_r;
  const float* bias = (bx < 4) ? bq_r : bk_r;
  float* C          = (bx < 4) ? S0 : S1;
  const int row0 = by * 128, col0 = (bx & 3) * 128;

  const int a_r = tid >> 2, a_k4 = (tid & 3) << 2;
  const int g0 = row0 + a_r, g1 = g0 + 64;
  const size_t ag0 = ((size_t)(g0 >> 8) * 257 + (g0 & 255) + 1) * DD + a_k4;
  const size_t ag1 = ((size_t)(g1 >> 8) * 257 + (g1 & 255) + 1) * DD + a_k4;
  const int b_kr = tid >> 5, b_c4 = (tid & 31) << 2;
  const size_t bg0 = (size_t)b_kr * DD + col0 + b_c4;
  const size_t bg1 = bg0 + (size_t)8 * DD;

  float acc[8][8] = {};

  float4 pa0 = *(const float4*)(x + ag0);
  float4 pa1 = *(const float4*)(x + ag1);
  float4 pb0 = *(const float4*)(Wm + bg0);
  float4 pb1 = *(const float4*)(Wm + bg1);

  for (int t = 0; t < 32; ++t) {
    const int buf = t & 1;
    As[buf][a_k4 + 0][a_r] = pa0.x;
    As[buf][a_k4 + 1][a_r] = pa0.y;
    As[buf][a_k4 + 2][a_r] = pa0.z;
    As[buf][a_k4 + 3][a_r] = pa0.w;
    As[buf][a_k4 + 0][a_r + 64] = pa1.x;
    As[buf][a_k4 + 1][a_r + 64] = pa1.y;
    As[buf][a_k4 + 2][a_r + 64] = pa1.z;
    As[buf][a_k4 + 3][a_r + 64] = pa1.w;
    *(float4*)&Bs[buf][b_kr][b_c4] = pb0;
    *(float4*)&Bs[buf][b_kr + 8][b_c4] = pb1;
    __syncthreads();

    if (t < 31) {
      const int k0 = (t + 1) << 4;
      pa0 = *(const float4*)(x + ag0 + k0);
      pa1 = *(const float4*)(x + ag1 + k0);
      pb0 = *(const float4*)(Wm + bg0 + (size_t)k0 * DD);
      pb1 = *(const float4*)(Wm + bg1 + (size_t)k0 * DD);
    }

#pragma unroll
    for (int kk = 0; kk < 16; ++kk) {
      float4 x0 = *(const float4*)&As[buf][kk][ty * 4];
      float4 x1 = *(const float4*)&As[buf][kk][ty * 4 + 64];
      float4 y0 = *(const float4*)&Bs[buf][kk][tx * 4];
      float4 y1 = *(const float4*)&Bs[buf][kk][tx * 4 + 64];
      float av[8] = {x0.x, x0.y, x0.z, x0.w, x1.x, x1.y, x1.z, x1.w};
      float bv[8] = {y0.x, y0.y, y0.z, y0.w, y1.x, y1.y, y1.z, y1.w};
#pragma unroll
      for (int i = 0; i < 8; ++i)
#pragma unroll
        for (int j = 0; j < 8; ++j)
          acc[i][j] = fmaf(av[i], bv[j], acc[i][j]);
    }
  }

#pragma unroll
  for (int ib = 0; ib < 2; ++ib)
#pragma unroll
    for (int i = 0; i < 4; ++i) {
      const int r = row0 + ib * 64 + ty * 4 + i;
#pragma unroll
      for (int jb = 0; jb < 2; ++jb) {
        const int c = col0 + jb * 64 + tx * 4;
        float4 o;
        o.x = acc[ib * 4 + i][jb * 4 + 0] + bias[c + 0];
        o.y = acc[ib * 4 + i][jb * 4 + 1] + bias[c + 1];
        o.z = acc[ib * 4 + i][jb * 4 + 2] + bias[c + 2];
        o.w = acc[ib * 4 + i][jb * 4 + 3] + bias[c + 3];
        *(float4*)(C + (size_t)r * DD + c) = o;
      }
    }
}

// ---------------------------------------------------------------------------
// Batched scores GEMM (f32, 64x64 tiles, 1024 blocks) — R2-proven
// ---------------------------------------------------------------------------
__global__ __launch_bounds__(256) void gemm_scores(
    const float* __restrict__ Q, const float* __restrict__ Kr,
    float* __restrict__ S)
{
  __shared__ float As[16][65];
  __shared__ float Bs[16][65];
  const int b = blockIdx.z;
  const int tid = threadIdx.x;
  const int tx = tid & 15, ty = tid >> 4;
  const int p0 = blockIdx.y * 64, q0 = blockIdx.x * 64;
  const float* Qb = Q + (long)b * PB * DD;
  const float* Kb = Kr + (long)b * PB * DD;
  const int a_r = tid >> 2, a_k = (tid & 3) << 2;
  const int b_n = tid & 63, b_k4 = (tid >> 6) << 2;
  float acc[4][4] = {};

  for (int k0 = 0; k0 < DD; k0 += 16) {
    float4 av = *(const float4*)(Qb + (long)(p0 + a_r) * DD + k0 + a_k);
    As[a_k + 0][a_r] = av.x;
    As[a_k + 1][a_r] = av.y;
    As[a_k + 2][a_r] = av.z;
    As[a_k + 3][a_r] = av.w;
    float4 bv = *(const float4*)(Kb + (long)(q0 + b_n) * DD + k0 + b_k4);
    Bs[b_k4 + 0][b_n] = bv.x;
    Bs[b_k4 + 1][b_n] = bv.y;
    Bs[b_k4 + 2][b_n] = bv.z;
    Bs[b_k4 + 3][b_n] = bv.w;
    __syncthreads();
#pragma unroll
    for (int kk = 0; kk < 16; ++kk) {
      float a[4], b2[4];
#pragma unroll
      for (int i = 0; i < 4; ++i) a[i] = As[kk][ty * 4 + i];
#pragma unroll
      for (int j = 0; j < 4; ++j) b2[j] = Bs[kk][tx * 4 + j];
#pragma unroll
      for (int i = 0; i < 4; ++i)
#pragma unroll
        for (int j = 0; j < 4; ++j)
          acc[i][j] = fmaf(a[i], b2[j], acc[i][j]);
    }
    __syncthreads();
  }

  float* Sb = S + (long)b * PB * PB;
#pragma unroll
  for (int i = 0; i < 4; ++i) {
    int p = p0 + ty * 4 + i;
    int q = q0 + tx * 4;
    float4 o = make_float4(acc[i][0], acc[i][1], acc[i][2], acc[i][3]);
    *(float4*)(Sb + (long)p * PB + q) = o;
  }
}

// ---------------------------------------------------------------------------
// split xp (with +1 row mapping) into bf16 hi/lo planes
// ---------------------------------------------------------------------------
__global__ __launch_bounds__(256) void split_x(
    const float* __restrict__ x, unsigned short* __restrict__ hi,
    unsigned short* __restrict__ lo)
{
  size_t i = (size_t)blockIdx.x * 256 + threadIdx.x;
  int row = (int)(i >> 6);
  int col = ((int)i & 63) << 3;
  const float* src = x + ((size_t)(row >> 8) * 257 + (row & 255) + 1) * DD + col;
  float4 a = *(const float4*)src;
  float4 b = *(const float4*)(src + 4);
  float v[8] = {a.x, a.y, a.z, a.w, b.x, b.y, b.z, b.w};
  us8 H, L;
#pragma unroll
  for (int j = 0; j < 8; ++j) {
    unsigned short h = f2b(v[j]);
    H[j] = h;
    L[j] = f2b(v[j] - b2f(h));
  }
  size_t o = (size_t)row * DD + col;
  *(us8*)(hi + o) = H;
  *(us8*)(lo + o) = L;
}

// ---------------------------------------------------------------------------
// split + TRANSPOSE a 512x512 weight into bf16 hi/lo planes: out[c][k]=W[k][c]
// ---------------------------------------------------------------------------
__global__ __launch_bounds__(256) void split_w(
    const float* __restrict__ W, unsigned short* __restrict__ hiT,
    unsigned short* __restrict__ loT)
{
  __shared__ float T[64][65];
  const int t = threadIdx.x;
  const int r0 = blockIdx.y * 64, c0 = blockIdx.x * 64;
  const int lr = t >> 2, lc4 = (t & 3) << 4;
#pragma unroll
  for (int j = 0; j < 4; ++j) {
    float4 v = *(const float4*)(W + (size_t)(r0 + lr) * DD + c0 + lc4 + j * 4);
    T[lr][lc4 + j * 4 + 0] = v.x;
    T[lr][lc4 + j * 4 + 1] = v.y;
    T[lr][lc4 + j * 4 + 2] = v.z;
    T[lr][lc4 + j * 4 + 3] = v.w;
  }
  __syncthreads();
  us8 H0, L0, H1, L1;
#pragma unroll
  for (int j = 0; j < 8; ++j) {
    float v0 = T[lc4 + j][lr];
    float v1 = T[lc4 + 8 + j][lr];
    unsigned short h0 = f2b(v0), h1 = f2b(v1);
    H0[j] = h0; L0[j] = f2b(v0 - b2f(h0));
    H1[j] = h1; L1[j] = f2b(v1 - b2f(h1));
  }
  size_t o = (size_t)(c0 + lr) * DD + r0 + lc4;
  *(us8*)(hiT + o) = H0;
  *(us8*)(hiT + o + 8) = H1;
  *(us8*)(loT + o) = L0;
  *(us8*)(loT + o + 8) = L1;
}

// ---------------------------------------------------------------------------
// bf16x3 split MFMA GEMM, MULTI-WEIGHT, NEW: B fragments read DIRECTLY from
// global (weights are 0.5 MB/plane -> fully L2-resident per XCD). A stays
// via global_load_lds + swizzled LDS (proven). Halves gload16 count and LDS
// (16 KB), removes B from the barrier-drained path. MFMA chain per output
// (hihi -> hilo -> lohi, ascending k0) unchanged -> bit-identical output.
// ---------------------------------------------------------------------------
template<int NW>
__global__ __launch_bounds__(256) void gemm3m(
    const unsigned short* __restrict__ Ahi, const unsigned short* __restrict__ Alo,
    const unsigned short* __restrict__ B0h, const unsigned short* __restrict__ B0l,
    const unsigned short* __restrict__ B1h, const unsigned short* __restrict__ B1l,
    const unsigned short* __restrict__ B2h, const unsigned short* __restrict__ B2l,
    const float* __restrict__ bias0, const float* __restrict__ bias1,
    const float* __restrict__ bias2,
    float* __restrict__ C0, float* __restrict__ C1, float* __restrict__ C2)
{
  __shared__ unsigned short Ah[128 * 32], Al[128 * 32];   // 16 KB total
  const int tid = threadIdx.x;
  const int wave = tid >> 6, lane = tid & 63;
  const int wr = wave >> 1, wc = wave & 1;

  const int lid = blockIdx.y * (4 * NW) + blockIdx.x;
  const int swz = (lid & 7) * (64 * NW) + (lid >> 3);
  const int wsel = swz >> 9;
  const int r9 = swz & 511;
  const int row0 = (r9 >> 2) * 128, col0 = (r9 & 3) * 128;

  const unsigned short* BhiT = (NW == 1 || wsel == 0) ? B0h : (wsel == 1) ? B1h : B2h;
  const unsigned short* BloT = (NW == 1 || wsel == 0) ? B0l : (wsel == 1) ? B1l : B2l;
  const float* bias          = (NW == 1 || wsel == 0) ? bias0 : (wsel == 1) ? bias1 : bias2;
  float* C                   = (NW == 1 || wsel == 0) ? C0 : (wsel == 1) ? C1 : C2;

  const int lr = lane & 15, lk = lane >> 4;
  f32x4 acc[4][4] = {};

  // A staging (unchanged, proven): pre-swizzled source, linear LDS dest
  const int sr = tid >> 2;
  const int schunk = (tid & 3) ^ ((sr >> 1) & 3);
  const unsigned int lds0 = (unsigned int)wave * 512;
  const size_t ga0 = (size_t)(row0 + sr) * DD + (schunk << 3);
  const size_t ga1 = ga0 + (size_t)64 * DD;

  int aoff[4];
#pragma unroll
  for (int m = 0; m < 4; ++m) {
    int row = wr * 64 + m * 16 + lr;
    aoff[m] = row * 32 + ((lk ^ ((row >> 1) & 3)) << 3);
  }
  // B fragment global offsets: row (col0 + wc*64 + n*16 + lr), k-chunk lk*8
  size_t bgo[4];
#pragma unroll
  for (int n = 0; n < 4; ++n)
    bgo[n] = (size_t)(col0 + wc * 64 + n * 16 + lr) * DD + (lk << 3);

  for (int k0 = 0; k0 < DD; k0 += 32) {
    gload16(Ahi + ga0 + k0, Ah + lds0);
    gload16(Ahi + ga1 + k0, Ah + lds0 + 2048);
    gload16(Alo + ga0 + k0, Al + lds0);
    gload16(Alo + ga1 + k0, Al + lds0 + 2048);

    // B frags straight from global (L2-hit); no LDS round-trip
    bf16x8 b[8];
#pragma unroll
    for (int n = 0; n < 4; ++n) {
      b[n]     = *(const bf16x8*)(BhiT + bgo[n] + k0);
      b[n + 4] = *(const bf16x8*)(BloT + bgo[n] + k0);
    }
    __syncthreads();

    bf16x8 a[8];
#pragma unroll
    for (int m = 0; m < 4; ++m) {
      a[m]     = *(const bf16x8*)(Ah + aoff[m]);
      a[m + 4] = *(const bf16x8*)(Al + aoff[m]);
    }
#pragma unroll
    for (int m = 0; m < 4; ++m)
#pragma unroll
      for (int n = 0; n < 4; ++n) {
        f32x4 c = acc[m][n];
        c = __builtin_amdgcn_mfma_f32_16x16x32_bf16(a[m],     b[n],     c, 0, 0, 0);
        c = __builtin_amdgcn_mfma_f32_16x16x32_bf16(a[m],     b[n + 4], c, 0, 0, 0);
        c = __builtin_amdgcn_mfma_f32_16x16x32_bf16(a[m + 4], b[n],     c, 0, 0, 0);
        acc[m][n] = c;
      }
    __syncthreads();
  }

  float bcol[4];
#pragma unroll
  for (int n = 0; n < 4; ++n) bcol[n] = bias[col0 + wc * 64 + n * 16 + lr];
#pragma unroll
  for (int m = 0; m < 4; ++m)
#pragma unroll
    for (int j = 0; j < 4; ++j) {
      int r = row0 + wr * 64 + m * 16 + lk * 4 + j;
#pragma unroll
      for (int n = 0; n < 4; ++n)
        C[(size_t)r * DD + col0 + wc * 64 + n * 16 + lr] = acc[m][n][j] + bcol[n];
    }
}

// ---------------------------------------------------------------------------
// l2norm (one dispatch over the contiguous S0|S1 region) / topk
// ---------------------------------------------------------------------------
__global__ __launch_bounds__(256) void l2norm_rows(float* __restrict__ X)
{
  const int row = blockIdx.x * 4 + (threadIdx.x >> 6);
  const int lane = threadIdx.x & 63;
  float* base = X + (long)row * DD + lane * 8;
  float4 u = *(float4*)base;
  float4 w = *(float4*)(base + 4);
  float s = u.x * u.x + u.y * u.y + u.z * u.z + u.w * u.w +
            w.x * w.x + w.y * w.y + w.z * w.z + w.w * w.w;
#pragma unroll
  for (int off = 1; off < 64; off <<= 1) s += __shfl_xor(s, off);
  float inv = 1.0f / sqrtf(s + 1e-12f);
  u.x *= inv; u.y *= inv; u.z *= inv; u.w *= inv;
  w.x *= inv; w.y *= inv; w.z *= inv; w.w *= inv;
  *(float4*)base = u;
  *(float4*)(base + 4) = w;
}

__global__ __launch_bounds__(256) void topk_routes(
    const float* __restrict__ S, const float* __restrict__ pb,
    int* __restrict__ routes)
{
  const int row = blockIdx.x * 4 + (threadIdx.x >> 6);
  const int lane = threadIdx.x & 63;
  const int p = row & 255;
  const float* srow = S + (long)row * 256;
  float v[4];
  int id[4];
#pragma unroll
  for (int i = 0; i < 4; ++i) {
    int q = i * 64 + lane;
    float s = srow[q] + pb[p * 256 + q];
    if (q == p) s = -1e9f;
    v[i] = s;
    id[i] = q;
  }
  for (int t = 0; t < 8; ++t) {
    float bv = v[0]; int bi = id[0]; int bs = 0;
#pragma unroll
    for (int i = 1; i < 4; ++i)
      if (v[i] > bv || (v[i] == bv && id[i] < bi)) { bv = v[i]; bi = id[i]; bs = i; }
    float rv = bv; int ri = bi;
#pragma unroll
    for (int off = 1; off < 64; off <<= 1) {
      float ov = __shfl_xor(rv, off);
      int oi = __shfl_xor(ri, off);
      if (ov > rv || (ov == rv && oi < ri)) { rv = ov; ri = oi; }
    }
    if (bi == ri) v[bs] = -INFINITY;
    if (lane == 0) routes[row * 8 + t] = ri;
  }
}

// ---------------------------------------------------------------------------
// Gathered 8-key attention; emits ctx as bf16 hi/lo planes for gemm3m.
// ---------------------------------------------------------------------------
__global__ __launch_bounds__(512) void wormhole_attn(
    const float* __restrict__ qh, const float* __restrict__ kh,
    const float* __restrict__ vh, const int* __restrict__ routes,
    unsigned short* __restrict__ chi, unsigned short* __restrict__ clo)
{
  const int bp = blockIdx.x;
  const int b = bp >> 8;
  const int tid = threadIdx.x;
  __shared__ int rs[8];
  if (tid < 8) rs[tid] = routes[bp * 8 + tid];
  __syncthreads();

  const float q = qh[(long)bp * DD + tid];
  long rbase[8];
  float s[8];
#pragma unroll
  for (int k = 0; k < 8; ++k) {
    long roff = ((long)((b << 8) | rs[k])) * DD + tid;
    rbase[k] = roff;
    float t = q * kh[roff];
#pragma unroll
    for (int off = 1; off < 64; off <<= 1) t += __shfl_xor(t, off);
    s[k] = t * 0.125f;
  }
  float m = s[0];
#pragma unroll
  for (int k = 1; k < 8; ++k) m = fmaxf(m, s[k]);
  float e[8], sum = 0.f;
#pragma unroll
  for (int k = 0; k < 8; ++k) { e[k] = expf(s[k] - m); sum += e[k]; }
  float inv = 1.0f / sum;
  float c = 0.f;
#pragma unroll
  for (int k = 0; k < 8; ++k) c = fmaf(e[k] * inv, vh[rbase[k]], c);
  unsigned short h = f2b(c);
  chi[(size_t)bp * DD + tid] = h;
  clo[(size_t)bp * DD + tid] = f2b(c - b2f(h));
}

// ---------------------------------------------------------------------------
extern "C" void kernel_launch(void* const* d_in, const int* in_sizes, int n_in,
                              void* d_out, int out_size, void* d_ws, size_t ws_size,
                              hipStream_t stream)
{
  const float* x        = (const float*)d_in[0];
  const float* wq_r     = (const float*)d_in[1];
  const float* bq_r     = (const float*)d_in[2];
  const float* wk_r     = (const float*)d_in[3];
  const float* bk_r     = (const float*)d_in[4];
  const float* pos_bias = (const float*)d_in[5];
  const float* wq       = (const float*)d_in[6];
  const float* bq       = (const float*)d_in[7];
  const float* wk       = (const float*)d_in[8];
  const float* bk       = (const float*)d_in[9];
  const float* wv       = (const float*)d_in[10];
  const float* bv       = (const float*)d_in[11];
  const float* wo       = (const float*)d_in[12];
  const float* bo       = (const float*)d_in[13];

  char* w = (char*)d_ws;
  const size_t SLOT = (size_t)MROWS * DD * sizeof(float);   // 33.55 MB
  unsigned short* Xhi = (unsigned short*)w;
  unsigned short* Xlo = (unsigned short*)(w + SLOT / 2);
  float* S0 = (float*)(w + SLOT);
  float* S1 = (float*)(w + 2 * SLOT);
  float* S2 = (float*)(w + 3 * SLOT);
  int* routes = (int*)(w + 4 * SLOT);
  const size_t WSZ = (size_t)DD * DD * sizeof(unsigned short);
  unsigned short* Wp = (unsigned short*)(w + 4 * SLOT + (1 << 20));
  unsigned short* Wq_hi = Wp + 0 * (WSZ / 2), *Wq_lo = Wp + 1 * (WSZ / 2);
  unsigned short* Wk_hi = Wp + 2 * (WSZ / 2), *Wk_lo = Wp + 3 * (WSZ / 2);
  unsigned short* Wv_hi = Wp + 4 * (WSZ / 2), *Wv_lo = Wp + 5 * (WSZ / 2);
  unsigned short* Wo_hi = Wp + 6 * (WSZ / 2), *Wo_lo = Wp + 7 * (WSZ / 2);

  unsigned short* Chi = Xhi;   // ctx reuses X region (X dead after vh GEMM)
  unsigned short* Clo = Xlo;

  dim3 blk(256);
  dim3 gw(8, 8);
  dim3 gr(8, 128);              // merged routing (R6-proven)
  dim3 gs(4, 4, 64);            // scores: 64x64 tiles x batch
  dim3 g3a(12, 128);            // gemm3m<3>: 1536 blocks
  dim3 g3b(4, 128);             // gemm3m<1>: 512 blocks

  // --- operand prep (bf16 hi/lo splits)
  split_x<<<4096, 256, 0, stream>>>(x, Xhi, Xlo);
  split_w<<<gw, 256, 0, stream>>>(wq, Wq_hi, Wq_lo);
  split_w<<<gw, 256, 0, stream>>>(wk, Wk_hi, Wk_lo);
  split_w<<<gw, 256, 0, stream>>>(wv, Wv_hi, Wv_lo);
  split_w<<<gw, 256, 0, stream>>>(wo, Wo_hi, Wo_lo);

  // --- routing path (f32; bit-identical fma order preserved)
  gemm_routing<<<gr, blk, 0, stream>>>(x, wq_r, bq_r, wk_r, bk_r, S0, S1);
  l2norm_rows<<<(2 * MROWS) / 4, 256, 0, stream>>>(S0);   // S0|S1 contiguous
  gemm_scores<<<gs, blk, 0, stream>>>(S0, S1, S2);
  topk_routes<<<MROWS / 4, 256, 0, stream>>>(S2, pos_bias, routes);

  // --- q,k,v head projections fused into ONE bf16x3 MFMA dispatch
  gemm3m<3><<<g3a, blk, 0, stream>>>(Xhi, Xlo,
      Wq_hi, Wq_lo, Wk_hi, Wk_lo, Wv_hi, Wv_lo,
      bq, bk, bv, S0, S1, S2);

  // --- gathered attention (emits ctx hi/lo) + output projection (MFMA)
  wormhole_attn<<<MROWS, 512, 0, stream>>>(S0, S1, S2, routes, Chi, Clo);
  gemm3m<1><<<g3b, blk, 0, stream>>>(Chi, Clo,
      Wo_hi, Wo_lo, Wo_hi, Wo_lo, Wo_hi, Wo_lo,
      bo, bo, bo, (float*)d_out, (float*)d_out, (float*)d_out);
}

// Round 9
// 522.856 us; speedup vs baseline: 1.4276x; 1.2857x over previous
//
#include <hip/hip_runtime.h>
#include <math.h>

constexpr int PB = 256;          // positions per batch
constexpr int DD = 512;          // model dim
constexpr int NB = 64;           // batch
constexpr int MROWS = NB * PB;   // 16384 rows

typedef __bf16 bf16x8 __attribute__((ext_vector_type(8)));
typedef float f32x4 __attribute__((ext_vector_type(4)));
typedef unsigned short us8 __attribute__((ext_vector_type(8)));

__device__ __forceinline__ unsigned short f2b(float f) {
  unsigned int u = __float_as_uint(f);
  u += 0x7FFFu + ((u >> 16) & 1u);        // round-to-nearest-even
  return (unsigned short)(u >> 16);
}
__device__ __forceinline__ float b2f(unsigned short h) {
  return __uint_as_float(((unsigned int)h) << 16);
}

// direct global->LDS DMA, 16B per lane; lds dest must be wave-uniform base
__device__ __forceinline__ void gload16(const void* g, const void* l) {
  __builtin_amdgcn_global_load_lds(
      (const __attribute__((address_space(1))) unsigned int*)(uintptr_t)g,
      (__attribute__((address_space(3))) unsigned int*)(unsigned int)(uintptr_t)l,
      16, 0, 0);
}

// ---------------------------------------------------------------------------
// Batched scores GEMM (f32, 64x64 tiles, 1024 blocks) — R2-proven.
// fmaf chain unchanged (scores numerics beyond q_r/k_r stay f32).
// ---------------------------------------------------------------------------
__global__ __launch_bounds__(256) void gemm_scores(
    const float* __restrict__ Q, const float* __restrict__ Kr,
    float* __restrict__ S)
{
  __shared__ float As[16][65];
  __shared__ float Bs[16][65];
  const int b = blockIdx.z;
  const int tid = threadIdx.x;
  const int tx = tid & 15, ty = tid >> 4;
  const int p0 = blockIdx.y * 64, q0 = blockIdx.x * 64;
  const float* Qb = Q + (long)b * PB * DD;
  const float* Kb = Kr + (long)b * PB * DD;
  const int a_r = tid >> 2, a_k = (tid & 3) << 2;
  const int b_n = tid & 63, b_k4 = (tid >> 6) << 2;
  float acc[4][4] = {};

  for (int k0 = 0; k0 < DD; k0 += 16) {
    float4 av = *(const float4*)(Qb + (long)(p0 + a_r) * DD + k0 + a_k);
    As[a_k + 0][a_r] = av.x;
    As[a_k + 1][a_r] = av.y;
    As[a_k + 2][a_r] = av.z;
    As[a_k + 3][a_r] = av.w;
    float4 bv = *(const float4*)(Kb + (long)(q0 + b_n) * DD + k0 + b_k4);
    Bs[b_k4 + 0][b_n] = bv.x;
    Bs[b_k4 + 1][b_n] = bv.y;
    Bs[b_k4 + 2][b_n] = bv.z;
    Bs[b_k4 + 3][b_n] = bv.w;
    __syncthreads();
#pragma unroll
    for (int kk = 0; kk < 16; ++kk) {
      float a[4], b2[4];
#pragma unroll
      for (int i = 0; i < 4; ++i) a[i] = As[kk][ty * 4 + i];
#pragma unroll
      for (int j = 0; j < 4; ++j) b2[j] = Bs[kk][tx * 4 + j];
#pragma unroll
      for (int i = 0; i < 4; ++i)
#pragma unroll
        for (int j = 0; j < 4; ++j)
          acc[i][j] = fmaf(a[i], b2[j], acc[i][j]);
    }
    __syncthreads();
  }

  float* Sb = S + (long)b * PB * PB;
#pragma unroll
  for (int i = 0; i < 4; ++i) {
    int p = p0 + ty * 4 + i;
    int q = q0 + tx * 4;
    float4 o = make_float4(acc[i][0], acc[i][1], acc[i][2], acc[i][3]);
    *(float4*)(Sb + (long)p * PB + q) = o;
  }
}

// ---------------------------------------------------------------------------
// split xp (with +1 row mapping) into bf16 hi/lo planes
// ---------------------------------------------------------------------------
__global__ __launch_bounds__(256) void split_x(
    const float* __restrict__ x, unsigned short* __restrict__ hi,
    unsigned short* __restrict__ lo)
{
  size_t i = (size_t)blockIdx.x * 256 + threadIdx.x;
  int row = (int)(i >> 6);
  int col = ((int)i & 63) << 3;
  const float* src = x + ((size_t)(row >> 8) * 257 + (row & 255) + 1) * DD + col;
  float4 a = *(const float4*)src;
  float4 b = *(const float4*)(src + 4);
  float v[8] = {a.x, a.y, a.z, a.w, b.x, b.y, b.z, b.w};
  us8 H, L;
#pragma unroll
  for (int j = 0; j < 8; ++j) {
    unsigned short h = f2b(v[j]);
    H[j] = h;
    L[j] = f2b(v[j] - b2f(h));
  }
  size_t o = (size_t)row * DD + col;
  *(us8*)(hi + o) = H;
  *(us8*)(lo + o) = L;
}

// ---------------------------------------------------------------------------
// split + TRANSPOSE a 512x512 weight into bf16 hi/lo planes: out[c][k]=W[k][c]
// ---------------------------------------------------------------------------
__global__ __launch_bounds__(256) void split_w(
    const float* __restrict__ W, unsigned short* __restrict__ hiT,
    unsigned short* __restrict__ loT)
{
  __shared__ float T[64][65];
  const int t = threadIdx.x;
  const int r0 = blockIdx.y * 64, c0 = blockIdx.x * 64;
  const int lr = t >> 2, lc4 = (t & 3) << 4;
#pragma unroll
  for (int j = 0; j < 4; ++j) {
    float4 v = *(const float4*)(W + (size_t)(r0 + lr) * DD + c0 + lc4 + j * 4);
    T[lr][lc4 + j * 4 + 0] = v.x;
    T[lr][lc4 + j * 4 + 1] = v.y;
    T[lr][lc4 + j * 4 + 2] = v.z;
    T[lr][lc4 + j * 4 + 3] = v.w;
  }
  __syncthreads();
  us8 H0, L0, H1, L1;
#pragma unroll
  for (int j = 0; j < 8; ++j) {
    float v0 = T[lc4 + j][lr];
    float v1 = T[lc4 + 8 + j][lr];
    unsigned short h0 = f2b(v0), h1 = f2b(v1);
    H0[j] = h0; L0[j] = f2b(v0 - b2f(h0));
    H1[j] = h1; L1[j] = f2b(v1 - b2f(h1));
  }
  size_t o = (size_t)(c0 + lr) * DD + r0 + lc4;
  *(us8*)(hiT + o) = H0;
  *(us8*)(hiT + o + 8) = H1;
  *(us8*)(loT + o) = L0;
  *(us8*)(loT + o + 8) = L1;
}

// ---------------------------------------------------------------------------
// bf16x3 split MFMA GEMM, MULTI-WEIGHT — R6-PROVEN BODY (LDS-staged B;
// the R8 reg-B variant regressed ~30 us). One dispatch computes NW
// projections of the same A. MFMA chain per output: hihi -> hilo -> lohi,
// ascending k0. Grid (4*NW, 128); bijective XCD swizzle over 512*NW blocks.
// Now also used for the ROUTING GEMMs (NW=2, B = wq_r/wk_r splits).
// ---------------------------------------------------------------------------
template<int NW>
__global__ __launch_bounds__(256) void gemm3m(
    const unsigned short* __restrict__ Ahi, const unsigned short* __restrict__ Alo,
    const unsigned short* __restrict__ B0h, const unsigned short* __restrict__ B0l,
    const unsigned short* __restrict__ B1h, const unsigned short* __restrict__ B1l,
    const unsigned short* __restrict__ B2h, const unsigned short* __restrict__ B2l,
    const float* __restrict__ bias0, const float* __restrict__ bias1,
    const float* __restrict__ bias2,
    float* __restrict__ C0, float* __restrict__ C1, float* __restrict__ C2)
{
  __shared__ unsigned short Ah[128 * 32], Al[128 * 32];
  __shared__ unsigned short Bh[128 * 32], Bl[128 * 32];
  const int tid = threadIdx.x;
  const int wave = tid >> 6, lane = tid & 63;
  const int wr = wave >> 1, wc = wave & 1;

  const int lid = blockIdx.y * (4 * NW) + blockIdx.x;
  const int swz = (lid & 7) * (64 * NW) + (lid >> 3);
  const int wsel = swz >> 9;
  const int r9 = swz & 511;
  const int row0 = (r9 >> 2) * 128, col0 = (r9 & 3) * 128;

  const unsigned short* BhiT = (NW == 1 || wsel == 0) ? B0h : (wsel == 1) ? B1h : B2h;
  const unsigned short* BloT = (NW == 1 || wsel == 0) ? B0l : (wsel == 1) ? B1l : B2l;
  const float* bias          = (NW == 1 || wsel == 0) ? bias0 : (wsel == 1) ? bias1 : bias2;
  float* C                   = (NW == 1 || wsel == 0) ? C0 : (wsel == 1) ? C1 : C2;

  const int lr = lane & 15, lk = lane >> 4;
  f32x4 acc[4][4] = {};

  const int sr = tid >> 2;
  const int schunk = (tid & 3) ^ ((sr >> 1) & 3);
  const unsigned int lds0 = (unsigned int)wave * 512;
  const size_t ga0 = (size_t)(row0 + sr) * DD + (schunk << 3);
  const size_t ga1 = ga0 + (size_t)64 * DD;
  const size_t gb0 = (size_t)(col0 + sr) * DD + (schunk << 3);
  const size_t gb1 = gb0 + (size_t)64 * DD;

  int aoff[4], boff[4];
#pragma unroll
  for (int m = 0; m < 4; ++m) {
    int row = wr * 64 + m * 16 + lr;
    aoff[m] = row * 32 + ((lk ^ ((row >> 1) & 3)) << 3);
  }
#pragma unroll
  for (int n = 0; n < 4; ++n) {
    int row = wc * 64 + n * 16 + lr;
    boff[n] = row * 32 + ((lk ^ ((row >> 1) & 3)) << 3);
  }

  for (int k0 = 0; k0 < DD; k0 += 32) {
    gload16(Ahi + ga0 + k0, Ah + lds0);
    gload16(Ahi + ga1 + k0, Ah + lds0 + 2048);
    gload16(Alo + ga0 + k0, Al + lds0);
    gload16(Alo + ga1 + k0, Al + lds0 + 2048);
    gload16(BhiT + gb0 + k0, Bh + lds0);
    gload16(BhiT + gb1 + k0, Bh + lds0 + 2048);
    gload16(BloT + gb0 + k0, Bl + lds0);
    gload16(BloT + gb1 + k0, Bl + lds0 + 2048);
    __syncthreads();

    bf16x8 a[8], b[8];
#pragma unroll
    for (int m = 0; m < 4; ++m) {
      a[m]     = *(const bf16x8*)(Ah + aoff[m]);
      a[m + 4] = *(const bf16x8*)(Al + aoff[m]);
    }
#pragma unroll
    for (int n = 0; n < 4; ++n) {
      b[n]     = *(const bf16x8*)(Bh + boff[n]);
      b[n + 4] = *(const bf16x8*)(Bl + boff[n]);
    }
#pragma unroll
    for (int m = 0; m < 4; ++m)
#pragma unroll
      for (int n = 0; n < 4; ++n) {
        f32x4 c = acc[m][n];
        c = __builtin_amdgcn_mfma_f32_16x16x32_bf16(a[m],     b[n],     c, 0, 0, 0);
        c = __builtin_amdgcn_mfma_f32_16x16x32_bf16(a[m],     b[n + 4], c, 0, 0, 0);
        c = __builtin_amdgcn_mfma_f32_16x16x32_bf16(a[m + 4], b[n],     c, 0, 0, 0);
        acc[m][n] = c;
      }
    __syncthreads();
  }

  float bcol[4];
#pragma unroll
  for (int n = 0; n < 4; ++n) bcol[n] = bias[col0 + wc * 64 + n * 16 + lr];
#pragma unroll
  for (int m = 0; m < 4; ++m)
#pragma unroll
    for (int j = 0; j < 4; ++j) {
      int r = row0 + wr * 64 + m * 16 + lk * 4 + j;
#pragma unroll
      for (int n = 0; n < 4; ++n)
        C[(size_t)r * DD + col0 + wc * 64 + n * 16 + lr] = acc[m][n][j] + bcol[n];
    }
}

// ---------------------------------------------------------------------------
// l2norm (one dispatch over the contiguous S0|S1 region) / topk
// ---------------------------------------------------------------------------
__global__ __launch_bounds__(256) void l2norm_rows(float* __restrict__ X)
{
  const int row = blockIdx.x * 4 + (threadIdx.x >> 6);
  const int lane = threadIdx.x & 63;
  float* base = X + (long)row * DD + lane * 8;
  float4 u = *(float4*)base;
  float4 w = *(float4*)(base + 4);
  float s = u.x * u.x + u.y * u.y + u.z * u.z + u.w * u.w +
            w.x * w.x + w.y * w.y + w.z * w.z + w.w * w.w;
#pragma unroll
  for (int off = 1; off < 64; off <<= 1) s += __shfl_xor(s, off);
  float inv = 1.0f / sqrtf(s + 1e-12f);
  u.x *= inv; u.y *= inv; u.z *= inv; u.w *= inv;
  w.x *= inv; w.y *= inv; w.z *= inv; w.w *= inv;
  *(float4*)base = u;
  *(float4*)(base + 4) = w;
}

__global__ __launch_bounds__(256) void topk_routes(
    const float* __restrict__ S, const float* __restrict__ pb,
    int* __restrict__ routes)
{
  const int row = blockIdx.x * 4 + (threadIdx.x >> 6);
  const int lane = threadIdx.x & 63;
  const int p = row & 255;
  const float* srow = S + (long)row * 256;
  float v[4];
  int id[4];
#pragma unroll
  for (int i = 0; i < 4; ++i) {
    int q = i * 64 + lane;
    float s = srow[q] + pb[p * 256 + q];
    if (q == p) s = -1e9f;
    v[i] = s;
    id[i] = q;
  }
  for (int t = 0; t < 8; ++t) {
    float bv = v[0]; int bi = id[0]; int bs = 0;
#pragma unroll
    for (int i = 1; i < 4; ++i)
      if (v[i] > bv || (v[i] == bv && id[i] < bi)) { bv = v[i]; bi = id[i]; bs = i; }
    float rv = bv; int ri = bi;
#pragma unroll
    for (int off = 1; off < 64; off <<= 1) {
      float ov = __shfl_xor(rv, off);
      int oi = __shfl_xor(ri, off);
      if (ov > rv || (ov == rv && oi < ri)) { rv = ov; ri = oi; }
    }
    if (bi == ri) v[bs] = -INFINITY;
    if (lane == 0) routes[row * 8 + t] = ri;
  }
}

// ---------------------------------------------------------------------------
// Gathered 8-key attention; emits ctx as bf16 hi/lo planes for gemm3m.
// ---------------------------------------------------------------------------
__global__ __launch_bounds__(512) void wormhole_attn(
    const float* __restrict__ qh, const float* __restrict__ kh,
    const float* __restrict__ vh, const int* __restrict__ routes,
    unsigned short* __restrict__ chi, unsigned short* __restrict__ clo)
{
  const int bp = blockIdx.x;
  const int b = bp >> 8;
  const int tid = threadIdx.x;
  __shared__ int rs[8];
  if (tid < 8) rs[tid] = routes[bp * 8 + tid];
  __syncthreads();

  const float q = qh[(long)bp * DD + tid];
  long rbase[8];
  float s[8];
#pragma unroll
  for (int k = 0; k < 8; ++k) {
    long roff = ((long)((b << 8) | rs[k])) * DD + tid;
    rbase[k] = roff;
    float t = q * kh[roff];
#pragma unroll
    for (int off = 1; off < 64; off <<= 1) t += __shfl_xor(t, off);
    s[k] = t * 0.125f;
  }
  float m = s[0];
#pragma unroll
  for (int k = 1; k < 8; ++k) m = fmaxf(m, s[k]);
  float e[8], sum = 0.f;
#pragma unroll
  for (int k = 0; k < 8; ++k) { e[k] = expf(s[k] - m); sum += e[k]; }
  float inv = 1.0f / sum;
  float c = 0.f;
#pragma unroll
  for (int k = 0; k < 8; ++k) c = fmaf(e[k] * inv, vh[rbase[k]], c);
  unsigned short h = f2b(c);
  chi[(size_t)bp * DD + tid] = h;
  clo[(size_t)bp * DD + tid] = f2b(c - b2f(h));
}

// ---------------------------------------------------------------------------
extern "C" void kernel_launch(void* const* d_in, const int* in_sizes, int n_in,
                              void* d_out, int out_size, void* d_ws, size_t ws_size,
                              hipStream_t stream)
{
  const float* x        = (const float*)d_in[0];
  const float* wq_r     = (const float*)d_in[1];
  const float* bq_r     = (const float*)d_in[2];
  const float* wk_r     = (const float*)d_in[3];
  const float* bk_r     = (const float*)d_in[4];
  const float* pos_bias = (const float*)d_in[5];
  const float* wq       = (const float*)d_in[6];
  const float* bq       = (const float*)d_in[7];
  const float* wk       = (const float*)d_in[8];
  const float* bk       = (const float*)d_in[9];
  const float* wv       = (const float*)d_in[10];
  const float* bv       = (const float*)d_in[11];
  const float* wo       = (const float*)d_in[12];
  const float* bo       = (const float*)d_in[13];

  char* w = (char*)d_ws;
  const size_t SLOT = (size_t)MROWS * DD * sizeof(float);   // 33.55 MB
  unsigned short* Xhi = (unsigned short*)w;
  unsigned short* Xlo = (unsigned short*)(w + SLOT / 2);
  float* S0 = (float*)(w + SLOT);
  float* S1 = (float*)(w + 2 * SLOT);
  float* S2 = (float*)(w + 3 * SLOT);
  int* routes = (int*)(w + 4 * SLOT);
  const size_t WSZ = (size_t)DD * DD * sizeof(unsigned short);  // 512 KB
  unsigned short* Wp = (unsigned short*)(w + 4 * SLOT + (1 << 20));
  unsigned short* Wq_hi = Wp + 0 * (WSZ / 2), *Wq_lo = Wp + 1 * (WSZ / 2);
  unsigned short* Wk_hi = Wp + 2 * (WSZ / 2), *Wk_lo = Wp + 3 * (WSZ / 2);
  unsigned short* Wv_hi = Wp + 4 * (WSZ / 2), *Wv_lo = Wp + 5 * (WSZ / 2);
  unsigned short* Wo_hi = Wp + 6 * (WSZ / 2), *Wo_lo = Wp + 7 * (WSZ / 2);

  // routing-weight splits live in S2's UPPER half (scores use only the lower
  // 16 MB of the 33.5 MB slot; dead by the time gemm3m<3> overwrites S2)
  unsigned short* Wr = (unsigned short*)(w + 3 * SLOT + SLOT / 2);
  unsigned short* Wqr_hi = Wr + 0 * (WSZ / 2), *Wqr_lo = Wr + 1 * (WSZ / 2);
  unsigned short* Wkr_hi = Wr + 2 * (WSZ / 2), *Wkr_lo = Wr + 3 * (WSZ / 2);

  unsigned short* Chi = Xhi;   // ctx reuses X region (X dead after vh GEMM)
  unsigned short* Clo = Xlo;

  dim3 blk(256);
  dim3 gw(8, 8);
  dim3 gs(4, 4, 64);            // scores: 64x64 tiles x batch
  dim3 g3r(8, 128);             // gemm3m<2>: 1024 blocks (routing)
  dim3 g3a(12, 128);            // gemm3m<3>: 1536 blocks
  dim3 g3b(4, 128);             // gemm3m<1>: 512 blocks

  // --- operand prep (bf16 hi/lo splits)
  split_x<<<4096, 256, 0, stream>>>(x, Xhi, Xlo);
  split_w<<<gw, 256, 0, stream>>>(wq_r, Wqr_hi, Wqr_lo);
  split_w<<<gw, 256, 0, stream>>>(wk_r, Wkr_hi, Wkr_lo);
  split_w<<<gw, 256, 0, stream>>>(wq, Wq_hi, Wq_lo);
  split_w<<<gw, 256, 0, stream>>>(wk, Wk_hi, Wk_lo);
  split_w<<<gw, 256, 0, stream>>>(wv, Wv_hi, Wv_lo);
  split_w<<<gw, 256, 0, stream>>>(wo, Wo_hi, Wo_lo);

  // --- routing path: q_r/k_r projections now bf16x3 MFMA (THE experiment)
  gemm3m<2><<<g3r, blk, 0, stream>>>(Xhi, Xlo,
      Wqr_hi, Wqr_lo, Wkr_hi, Wkr_lo, Wkr_hi, Wkr_lo,
      bq_r, bk_r, bk_r, S0, S1, S1);
  l2norm_rows<<<(2 * MROWS) / 4, 256, 0, stream>>>(S0);   // S0|S1 contiguous
  gemm_scores<<<gs, blk, 0, stream>>>(S0, S1, S2);
  topk_routes<<<MROWS / 4, 256, 0, stream>>>(S2, pos_bias, routes);

  // --- q,k,v head projections fused into ONE bf16x3 MFMA dispatch
  gemm3m<3><<<g3a, blk, 0, stream>>>(Xhi, Xlo,
      Wq_hi, Wq_lo, Wk_hi, Wk_lo, Wv_hi, Wv_lo,
      bq, bk, bv, S0, S1, S2);

  // --- gathered attention (emits ctx hi/lo) + output projection (MFMA)
  wormhole_attn<<<MROWS, 512, 0, stream>>>(S0, S1, S2, routes, Chi, Clo);
  gemm3m<1><<<g3b, blk, 0, stream>>>(Chi, Clo,
      Wo_hi, Wo_lo, Wo_hi, Wo_lo, Wo_hi, Wo_lo,
      bo, bo, bo, (float*)d_out, (float*)d_out, (float*)d_out);
}

// Round 10
// 467.892 us; speedup vs baseline: 1.5953x; 1.1175x over previous
//
#include <hip/hip_runtime.h>
#include <math.h>

constexpr int PB = 256;          // positions per batch
constexpr int DD = 512;          // model dim
constexpr int NB = 64;           // batch
constexpr int MROWS = NB * PB;   // 16384 rows

typedef __bf16 bf16x8 __attribute__((ext_vector_type(8)));
typedef float f32x4 __attribute__((ext_vector_type(4)));
typedef unsigned short us8 __attribute__((ext_vector_type(8)));

__device__ __forceinline__ unsigned short f2b(float f) {
  unsigned int u = __float_as_uint(f);
  u += 0x7FFFu + ((u >> 16) & 1u);        // round-to-nearest-even
  return (unsigned short)(u >> 16);
}
__device__ __forceinline__ float b2f(unsigned short h) {
  return __uint_as_float(((unsigned int)h) << 16);
}

// direct global->LDS DMA, 16B per lane; lds dest must be wave-uniform base
__device__ __forceinline__ void gload16(const void* g, const void* l) {
  __builtin_amdgcn_global_load_lds(
      (const __attribute__((address_space(1))) unsigned int*)(uintptr_t)g,
      (__attribute__((address_space(3))) unsigned int*)(unsigned int)(uintptr_t)l,
      16, 0, 0);
}

// ---------------------------------------------------------------------------
// Batched scores GEMM (f32, 64x64 tiles, 1024 blocks).
// R10: LDS rows padded 65 -> 68 floats (272 B, 16B-aligned) and inner-loop
// reads converted to ds_read_b128 (2/kk instead of 8 ds_read_b32) -- the
// kernel was LDS-instruction-bound (VALUBusy 30%). Same values, same fmaf
// order (ascending k) -> BIT-IDENTICAL output to R9's passing kernel.
// ---------------------------------------------------------------------------
__global__ __launch_bounds__(256) void gemm_scores(
    const float* __restrict__ Q, const float* __restrict__ Kr,
    float* __restrict__ S)
{
  __shared__ float As[16][68];
  __shared__ float Bs[16][68];
  const int b = blockIdx.z;
  const int tid = threadIdx.x;
  const int tx = tid & 15, ty = tid >> 4;
  const int p0 = blockIdx.y * 64, q0 = blockIdx.x * 64;
  const float* Qb = Q + (long)b * PB * DD;
  const float* Kb = Kr + (long)b * PB * DD;
  const int a_r = tid >> 2, a_k = (tid & 3) << 2;
  const int b_n = tid & 63, b_k4 = (tid >> 6) << 2;
  float acc[4][4] = {};

  for (int k0 = 0; k0 < DD; k0 += 16) {
    float4 av = *(const float4*)(Qb + (long)(p0 + a_r) * DD + k0 + a_k);
    As[a_k + 0][a_r] = av.x;
    As[a_k + 1][a_r] = av.y;
    As[a_k + 2][a_r] = av.z;
    As[a_k + 3][a_r] = av.w;
    float4 bv = *(const float4*)(Kb + (long)(q0 + b_n) * DD + k0 + b_k4);
    Bs[b_k4 + 0][b_n] = bv.x;
    Bs[b_k4 + 1][b_n] = bv.y;
    Bs[b_k4 + 2][b_n] = bv.z;
    Bs[b_k4 + 3][b_n] = bv.w;
    __syncthreads();
#pragma unroll
    for (int kk = 0; kk < 16; ++kk) {
      float4 a4 = *(const float4*)&As[kk][ty * 4];   // 1 ds_read_b128
      float4 b4 = *(const float4*)&Bs[kk][tx * 4];   // 1 ds_read_b128
      float a[4]  = {a4.x, a4.y, a4.z, a4.w};
      float b2[4] = {b4.x, b4.y, b4.z, b4.w};
#pragma unroll
      for (int i = 0; i < 4; ++i)
#pragma unroll
        for (int j = 0; j < 4; ++j)
          acc[i][j] = fmaf(a[i], b2[j], acc[i][j]);
    }
    __syncthreads();
  }

  float* Sb = S + (long)b * PB * PB;
#pragma unroll
  for (int i = 0; i < 4; ++i) {
    int p = p0 + ty * 4 + i;
    int q = q0 + tx * 4;
    float4 o = make_float4(acc[i][0], acc[i][1], acc[i][2], acc[i][3]);
    *(float4*)(Sb + (long)p * PB + q) = o;
  }
}

// ---------------------------------------------------------------------------
// split xp (with +1 row mapping) into bf16 hi/lo planes
// ---------------------------------------------------------------------------
__global__ __launch_bounds__(256) void split_x(
    const float* __restrict__ x, unsigned short* __restrict__ hi,
    unsigned short* __restrict__ lo)
{
  size_t i = (size_t)blockIdx.x * 256 + threadIdx.x;
  int row = (int)(i >> 6);
  int col = ((int)i & 63) << 3;
  const float* src = x + ((size_t)(row >> 8) * 257 + (row & 255) + 1) * DD + col;
  float4 a = *(const float4*)src;
  float4 b = *(const float4*)(src + 4);
  float v[8] = {a.x, a.y, a.z, a.w, b.x, b.y, b.z, b.w};
  us8 H, L;
#pragma unroll
  for (int j = 0; j < 8; ++j) {
    unsigned short h = f2b(v[j]);
    H[j] = h;
    L[j] = f2b(v[j] - b2f(h));
  }
  size_t o = (size_t)row * DD + col;
  *(us8*)(hi + o) = H;
  *(us8*)(lo + o) = L;
}

// ---------------------------------------------------------------------------
// split + TRANSPOSE a 512x512 weight into bf16 hi/lo planes: out[c][k]=W[k][c]
// ---------------------------------------------------------------------------
__global__ __launch_bounds__(256) void split_w(
    const float* __restrict__ W, unsigned short* __restrict__ hiT,
    unsigned short* __restrict__ loT)
{
  __shared__ float T[64][65];
  const int t = threadIdx.x;
  const int r0 = blockIdx.y * 64, c0 = blockIdx.x * 64;
  const int lr = t >> 2, lc4 = (t & 3) << 4;
#pragma unroll
  for (int j = 0; j < 4; ++j) {
    float4 v = *(const float4*)(W + (size_t)(r0 + lr) * DD + c0 + lc4 + j * 4);
    T[lr][lc4 + j * 4 + 0] = v.x;
    T[lr][lc4 + j * 4 + 1] = v.y;
    T[lr][lc4 + j * 4 + 2] = v.z;
    T[lr][lc4 + j * 4 + 3] = v.w;
  }
  __syncthreads();
  us8 H0, L0, H1, L1;
#pragma unroll
  for (int j = 0; j < 8; ++j) {
    float v0 = T[lc4 + j][lr];
    float v1 = T[lc4 + 8 + j][lr];
    unsigned short h0 = f2b(v0), h1 = f2b(v1);
    H0[j] = h0; L0[j] = f2b(v0 - b2f(h0));
    H1[j] = h1; L1[j] = f2b(v1 - b2f(h1));
  }
  size_t o = (size_t)(c0 + lr) * DD + r0 + lc4;
  *(us8*)(hiT + o) = H0;
  *(us8*)(hiT + o + 8) = H1;
  *(us8*)(loT + o) = L0;
  *(us8*)(loT + o + 8) = L1;
}

// ---------------------------------------------------------------------------
// bf16x3 split MFMA GEMM, MULTI-WEIGHT — R6-PROVEN BODY (LDS-staged B).
// One dispatch computes NW projections of the same A. MFMA chain per output:
// hihi -> hilo -> lohi, ascending k0. Grid (4*NW, 128); bijective XCD swizzle.
// Used for routing (NW=2), head projections (NW=3), output proj (NW=1).
// ---------------------------------------------------------------------------
template<int NW>
__global__ __launch_bounds__(256) void gemm3m(
    const unsigned short* __restrict__ Ahi, const unsigned short* __restrict__ Alo,
    const unsigned short* __restrict__ B0h, const unsigned short* __restrict__ B0l,
    const unsigned short* __restrict__ B1h, const unsigned short* __restrict__ B1l,
    const unsigned short* __restrict__ B2h, const unsigned short* __restrict__ B2l,
    const float* __restrict__ bias0, const float* __restrict__ bias1,
    const float* __restrict__ bias2,
    float* __restrict__ C0, float* __restrict__ C1, float* __restrict__ C2)
{
  __shared__ unsigned short Ah[128 * 32], Al[128 * 32];
  __shared__ unsigned short Bh[128 * 32], Bl[128 * 32];
  const int tid = threadIdx.x;
  const int wave = tid >> 6, lane = tid & 63;
  const int wr = wave >> 1, wc = wave & 1;

  const int lid = blockIdx.y * (4 * NW) + blockIdx.x;
  const int swz = (lid & 7) * (64 * NW) + (lid >> 3);
  const int wsel = swz >> 9;
  const int r9 = swz & 511;
  const int row0 = (r9 >> 2) * 128, col0 = (r9 & 3) * 128;

  const unsigned short* BhiT = (NW == 1 || wsel == 0) ? B0h : (wsel == 1) ? B1h : B2h;
  const unsigned short* BloT = (NW == 1 || wsel == 0) ? B0l : (wsel == 1) ? B1l : B2l;
  const float* bias          = (NW == 1 || wsel == 0) ? bias0 : (wsel == 1) ? bias1 : bias2;
  float* C                   = (NW == 1 || wsel == 0) ? C0 : (wsel == 1) ? C1 : C2;

  const int lr = lane & 15, lk = lane >> 4;
  f32x4 acc[4][4] = {};

  const int sr = tid >> 2;
  const int schunk = (tid & 3) ^ ((sr >> 1) & 3);
  const unsigned int lds0 = (unsigned int)wave * 512;
  const size_t ga0 = (size_t)(row0 + sr) * DD + (schunk << 3);
  const size_t ga1 = ga0 + (size_t)64 * DD;
  const size_t gb0 = (size_t)(col0 + sr) * DD + (schunk << 3);
  const size_t gb1 = gb0 + (size_t)64 * DD;

  int aoff[4], boff[4];
#pragma unroll
  for (int m = 0; m < 4; ++m) {
    int row = wr * 64 + m * 16 + lr;
    aoff[m] = row * 32 + ((lk ^ ((row >> 1) & 3)) << 3);
  }
#pragma unroll
  for (int n = 0; n < 4; ++n) {
    int row = wc * 64 + n * 16 + lr;
    boff[n] = row * 32 + ((lk ^ ((row >> 1) & 3)) << 3);
  }

  for (int k0 = 0; k0 < DD; k0 += 32) {
    gload16(Ahi + ga0 + k0, Ah + lds0);
    gload16(Ahi + ga1 + k0, Ah + lds0 + 2048);
    gload16(Alo + ga0 + k0, Al + lds0);
    gload16(Alo + ga1 + k0, Al + lds0 + 2048);
    gload16(BhiT + gb0 + k0, Bh + lds0);
    gload16(BhiT + gb1 + k0, Bh + lds0 + 2048);
    gload16(BloT + gb0 + k0, Bl + lds0);
    gload16(BloT + gb1 + k0, Bl + lds0 + 2048);
    __syncthreads();

    bf16x8 a[8], b[8];
#pragma unroll
    for (int m = 0; m < 4; ++m) {
      a[m]     = *(const bf16x8*)(Ah + aoff[m]);
      a[m + 4] = *(const bf16x8*)(Al + aoff[m]);
    }
#pragma unroll
    for (int n = 0; n < 4; ++n) {
      b[n]     = *(const bf16x8*)(Bh + boff[n]);
      b[n + 4] = *(const bf16x8*)(Bl + boff[n]);
    }
#pragma unroll
    for (int m = 0; m < 4; ++m)
#pragma unroll
      for (int n = 0; n < 4; ++n) {
        f32x4 c = acc[m][n];
        c = __builtin_amdgcn_mfma_f32_16x16x32_bf16(a[m],     b[n],     c, 0, 0, 0);
        c = __builtin_amdgcn_mfma_f32_16x16x32_bf16(a[m],     b[n + 4], c, 0, 0, 0);
        c = __builtin_amdgcn_mfma_f32_16x16x32_bf16(a[m + 4], b[n],     c, 0, 0, 0);
        acc[m][n] = c;
      }
    __syncthreads();
  }

  float bcol[4];
#pragma unroll
  for (int n = 0; n < 4; ++n) bcol[n] = bias[col0 + wc * 64 + n * 16 + lr];
#pragma unroll
  for (int m = 0; m < 4; ++m)
#pragma unroll
    for (int j = 0; j < 4; ++j) {
      int r = row0 + wr * 64 + m * 16 + lk * 4 + j;
#pragma unroll
      for (int n = 0; n < 4; ++n)
        C[(size_t)r * DD + col0 + wc * 64 + n * 16 + lr] = acc[m][n][j] + bcol[n];
    }
}

// ---------------------------------------------------------------------------
// l2norm (one dispatch over the contiguous S0|S1 region) / topk
// ---------------------------------------------------------------------------
__global__ __launch_bounds__(256) void l2norm_rows(float* __restrict__ X)
{
  const int row = blockIdx.x * 4 + (threadIdx.x >> 6);
  const int lane = threadIdx.x & 63;
  float* base = X + (long)row * DD + lane * 8;
  float4 u = *(float4*)base;
  float4 w = *(float4*)(base + 4);
  float s = u.x * u.x + u.y * u.y + u.z * u.z + u.w * u.w +
            w.x * w.x + w.y * w.y + w.z * w.z + w.w * w.w;
#pragma unroll
  for (int off = 1; off < 64; off <<= 1) s += __shfl_xor(s, off);
  float inv = 1.0f / sqrtf(s + 1e-12f);
  u.x *= inv; u.y *= inv; u.z *= inv; u.w *= inv;
  w.x *= inv; w.y *= inv; w.z *= inv; w.w *= inv;
  *(float4*)base = u;
  *(float4*)(base + 4) = w;
}

__global__ __launch_bounds__(256) void topk_routes(
    const float* __restrict__ S, const float* __restrict__ pb,
    int* __restrict__ routes)
{
  const int row = blockIdx.x * 4 + (threadIdx.x >> 6);
  const int lane = threadIdx.x & 63;
  const int p = row & 255;
  const float* srow = S + (long)row * 256;
  float v[4];
  int id[4];
#pragma unroll
  for (int i = 0; i < 4; ++i) {
    int q = i * 64 + lane;
    float s = srow[q] + pb[p * 256 + q];
    if (q == p) s = -1e9f;
    v[i] = s;
    id[i] = q;
  }
  for (int t = 0; t < 8; ++t) {
    float bv = v[0]; int bi = id[0]; int bs = 0;
#pragma unroll
    for (int i = 1; i < 4; ++i)
      if (v[i] > bv || (v[i] == bv && id[i] < bi)) { bv = v[i]; bi = id[i]; bs = i; }
    float rv = bv; int ri = bi;
#pragma unroll
    for (int off = 1; off < 64; off <<= 1) {
      float ov = __shfl_xor(rv, off);
      int oi = __shfl_xor(ri, off);
      if (ov > rv || (ov == rv && oi < ri)) { rv = ov; ri = oi; }
    }
    if (bi == ri) v[bs] = -INFINITY;
    if (lane == 0) routes[row * 8 + t] = ri;
  }
}

// ---------------------------------------------------------------------------
// Gathered 8-key attention; emits ctx as bf16 hi/lo planes for gemm3m.
// ---------------------------------------------------------------------------
__global__ __launch_bounds__(512) void wormhole_attn(
    const float* __restrict__ qh, const float* __restrict__ kh,
    const float* __restrict__ vh, const int* __restrict__ routes,
    unsigned short* __restrict__ chi, unsigned short* __restrict__ clo)
{
  const int bp = blockIdx.x;
  const int b = bp >> 8;
  const int tid = threadIdx.x;
  __shared__ int rs[8];
  if (tid < 8) rs[tid] = routes[bp * 8 + tid];
  __syncthreads();

  const float q = qh[(long)bp * DD + tid];
  long rbase[8];
  float s[8];
#pragma unroll
  for (int k = 0; k < 8; ++k) {
    long roff = ((long)((b << 8) | rs[k])) * DD + tid;
    rbase[k] = roff;
    float t = q * kh[roff];
#pragma unroll
    for (int off = 1; off < 64; off <<= 1) t += __shfl_xor(t, off);
    s[k] = t * 0.125f;
  }
  float m = s[0];
#pragma unroll
  for (int k = 1; k < 8; ++k) m = fmaxf(m, s[k]);
  float e[8], sum = 0.f;
#pragma unroll
  for (int k = 0; k < 8; ++k) { e[k] = expf(s[k] - m); sum += e[k]; }
  float inv = 1.0f / sum;
  float c = 0.f;
#pragma unroll
  for (int k = 0; k < 8; ++k) c = fmaf(e[k] * inv, vh[rbase[k]], c);
  unsigned short h = f2b(c);
  chi[(size_t)bp * DD + tid] = h;
  clo[(size_t)bp * DD + tid] = f2b(c - b2f(h));
}

// ---------------------------------------------------------------------------
extern "C" void kernel_launch(void* const* d_in, const int* in_sizes, int n_in,
                              void* d_out, int out_size, void* d_ws, size_t ws_size,
                              hipStream_t stream)
{
  const float* x        = (const float*)d_in[0];
  const float* wq_r     = (const float*)d_in[1];
  const float* bq_r     = (const float*)d_in[2];
  const float* wk_r     = (const float*)d_in[3];
  const float* bk_r     = (const float*)d_in[4];
  const float* pos_bias = (const float*)d_in[5];
  const float* wq       = (const float*)d_in[6];
  const float* bq       = (const float*)d_in[7];
  const float* wk       = (const float*)d_in[8];
  const float* bk       = (const float*)d_in[9];
  const float* wv       = (const float*)d_in[10];
  const float* bv       = (const float*)d_in[11];
  const float* wo       = (const float*)d_in[12];
  const float* bo       = (const float*)d_in[13];

  char* w = (char*)d_ws;
  const size_t SLOT = (size_t)MROWS * DD * sizeof(float);   // 33.55 MB
  unsigned short* Xhi = (unsigned short*)w;
  unsigned short* Xlo = (unsigned short*)(w + SLOT / 2);
  float* S0 = (float*)(w + SLOT);
  float* S1 = (float*)(w + 2 * SLOT);
  float* S2 = (float*)(w + 3 * SLOT);
  int* routes = (int*)(w + 4 * SLOT);
  const size_t WSZ = (size_t)DD * DD * sizeof(unsigned short);  // 512 KB
  unsigned short* Wp = (unsigned short*)(w + 4 * SLOT + (1 << 20));
  unsigned short* Wq_hi = Wp + 0 * (WSZ / 2), *Wq_lo = Wp + 1 * (WSZ / 2);
  unsigned short* Wk_hi = Wp + 2 * (WSZ / 2), *Wk_lo = Wp + 3 * (WSZ / 2);
  unsigned short* Wv_hi = Wp + 4 * (WSZ / 2), *Wv_lo = Wp + 5 * (WSZ / 2);
  unsigned short* Wo_hi = Wp + 6 * (WSZ / 2), *Wo_lo = Wp + 7 * (WSZ / 2);

  // routing-weight splits live in S2's UPPER half (scores use only the lower
  // 16 MB of the 33.5 MB slot; dead by the time gemm3m<3> overwrites S2)
  unsigned short* Wr = (unsigned short*)(w + 3 * SLOT + SLOT / 2);
  unsigned short* Wqr_hi = Wr + 0 * (WSZ / 2), *Wqr_lo = Wr + 1 * (WSZ / 2);
  unsigned short* Wkr_hi = Wr + 2 * (WSZ / 2), *Wkr_lo = Wr + 3 * (WSZ / 2);

  unsigned short* Chi = Xhi;   // ctx reuses X region (X dead after vh GEMM)
  unsigned short* Clo = Xlo;

  dim3 blk(256);
  dim3 gw(8, 8);
  dim3 gs(4, 4, 64);            // scores: 64x64 tiles x batch
  dim3 g3r(8, 128);             // gemm3m<2>: 1024 blocks (routing)
  dim3 g3a(12, 128);            // gemm3m<3>: 1536 blocks
  dim3 g3b(4, 128);             // gemm3m<1>: 512 blocks

  // --- operand prep (bf16 hi/lo splits)
  split_x<<<4096, 256, 0, stream>>>(x, Xhi, Xlo);
  split_w<<<gw, 256, 0, stream>>>(wq_r, Wqr_hi, Wqr_lo);
  split_w<<<gw, 256, 0, stream>>>(wk_r, Wkr_hi, Wkr_lo);
  split_w<<<gw, 256, 0, stream>>>(wq, Wq_hi, Wq_lo);
  split_w<<<gw, 256, 0, stream>>>(wk, Wk_hi, Wk_lo);
  split_w<<<gw, 256, 0, stream>>>(wv, Wv_hi, Wv_lo);
  split_w<<<gw, 256, 0, stream>>>(wo, Wo_hi, Wo_lo);

  // --- routing path: q_r/k_r projections bf16x3 MFMA (R9-proven)
  gemm3m<2><<<g3r, blk, 0, stream>>>(Xhi, Xlo,
      Wqr_hi, Wqr_lo, Wkr_hi, Wkr_lo, Wkr_hi, Wkr_lo,
      bq_r, bk_r, bk_r, S0, S1, S1);
  l2norm_rows<<<(2 * MROWS) / 4, 256, 0, stream>>>(S0);   // S0|S1 contiguous
  gemm_scores<<<gs, blk, 0, stream>>>(S0, S1, S2);
  topk_routes<<<MROWS / 4, 256, 0, stream>>>(S2, pos_bias, routes);

  // --- q,k,v head projections fused into ONE bf16x3 MFMA dispatch
  gemm3m<3><<<g3a, blk, 0, stream>>>(Xhi, Xlo,
      Wq_hi, Wq_lo, Wk_hi, Wk_lo, Wv_hi, Wv_lo,
      bq, bk, bv, S0, S1, S2);

  // --- gathered attention (emits ctx hi/lo) + output projection (MFMA)
  wormhole_attn<<<MROWS, 512, 0, stream>>>(S0, S1, S2, routes, Chi, Clo);
  gemm3m<1><<<g3b, blk, 0, stream>>>(Chi, Clo,
      Wo_hi, Wo_lo, Wo_hi, Wo_lo, Wo_hi, Wo_lo,
      bo, bo, bo, (float*)d_out, (float*)d_out, (float*)d_out);
}

// Round 11
// 443.187 us; speedup vs baseline: 1.6842x; 1.0557x over previous
//
#include <hip/hip_runtime.h>
#include <math.h>

constexpr int PB = 256;          // positions per batch
constexpr int DD = 512;          // model dim
constexpr int NB = 64;           // batch
constexpr int MROWS = NB * PB;   // 16384 rows

typedef __bf16 bf16x8 __attribute__((ext_vector_type(8)));
typedef float f32x4 __attribute__((ext_vector_type(4)));
typedef unsigned short us8 __attribute__((ext_vector_type(8)));

__device__ __forceinline__ unsigned short f2b(float f) {
  unsigned int u = __float_as_uint(f);
  u += 0x7FFFu + ((u >> 16) & 1u);        // round-to-nearest-even
  return (unsigned short)(u >> 16);
}
__device__ __forceinline__ float b2f(unsigned short h) {
  return __uint_as_float(((unsigned int)h) << 16);
}

// direct global->LDS DMA, 16B per lane; lds dest must be wave-uniform base
__device__ __forceinline__ void gload16(const void* g, const void* l) {
  __builtin_amdgcn_global_load_lds(
      (const __attribute__((address_space(1))) unsigned int*)(uintptr_t)g,
      (__attribute__((address_space(3))) unsigned int*)(unsigned int)(uintptr_t)l,
      16, 0, 0);
}

// ---------------------------------------------------------------------------
// split xp (with +1 row mapping) into bf16 hi/lo planes
// ---------------------------------------------------------------------------
__global__ __launch_bounds__(256) void split_x(
    const float* __restrict__ x, unsigned short* __restrict__ hi,
    unsigned short* __restrict__ lo)
{
  size_t i = (size_t)blockIdx.x * 256 + threadIdx.x;
  int row = (int)(i >> 6);
  int col = ((int)i & 63) << 3;
  const float* src = x + ((size_t)(row >> 8) * 257 + (row & 255) + 1) * DD + col;
  float4 a = *(const float4*)src;
  float4 b = *(const float4*)(src + 4);
  float v[8] = {a.x, a.y, a.z, a.w, b.x, b.y, b.z, b.w};
  us8 H, L;
#pragma unroll
  for (int j = 0; j < 8; ++j) {
    unsigned short h = f2b(v[j]);
    H[j] = h;
    L[j] = f2b(v[j] - b2f(h));
  }
  size_t o = (size_t)row * DD + col;
  *(us8*)(hi + o) = H;
  *(us8*)(lo + o) = L;
}

// ---------------------------------------------------------------------------
// split + TRANSPOSE a 512x512 weight into bf16 hi/lo planes: out[c][k]=W[k][c]
// ---------------------------------------------------------------------------
__global__ __launch_bounds__(256) void split_w(
    const float* __restrict__ W, unsigned short* __restrict__ hiT,
    unsigned short* __restrict__ loT)
{
  __shared__ float T[64][65];
  const int t = threadIdx.x;
  const int r0 = blockIdx.y * 64, c0 = blockIdx.x * 64;
  const int lr = t >> 2, lc4 = (t & 3) << 4;
#pragma unroll
  for (int j = 0; j < 4; ++j) {
    float4 v = *(const float4*)(W + (size_t)(r0 + lr) * DD + c0 + lc4 + j * 4);
    T[lr][lc4 + j * 4 + 0] = v.x;
    T[lr][lc4 + j * 4 + 1] = v.y;
    T[lr][lc4 + j * 4 + 2] = v.z;
    T[lr][lc4 + j * 4 + 3] = v.w;
  }
  __syncthreads();
  us8 H0, L0, H1, L1;
#pragma unroll
  for (int j = 0; j < 8; ++j) {
    float v0 = T[lc4 + j][lr];
    float v1 = T[lc4 + 8 + j][lr];
    unsigned short h0 = f2b(v0), h1 = f2b(v1);
    H0[j] = h0; L0[j] = f2b(v0 - b2f(h0));
    H1[j] = h1; L1[j] = f2b(v1 - b2f(h1));
  }
  size_t o = (size_t)(c0 + lr) * DD + r0 + lc4;
  *(us8*)(hiT + o) = H0;
  *(us8*)(hiT + o + 8) = H1;
  *(us8*)(loT + o) = L0;
  *(us8*)(loT + o + 8) = L1;
}

// ---------------------------------------------------------------------------
// bf16x3 split MFMA GEMM, MULTI-WEIGHT — R6-PROVEN BODY (LDS-staged B).
// MFMA chain per output: hihi -> hilo -> lohi, ascending k0.
// ---------------------------------------------------------------------------
template<int NW>
__global__ __launch_bounds__(256) void gemm3m(
    const unsigned short* __restrict__ Ahi, const unsigned short* __restrict__ Alo,
    const unsigned short* __restrict__ B0h, const unsigned short* __restrict__ B0l,
    const unsigned short* __restrict__ B1h, const unsigned short* __restrict__ B1l,
    const unsigned short* __restrict__ B2h, const unsigned short* __restrict__ B2l,
    const float* __restrict__ bias0, const float* __restrict__ bias1,
    const float* __restrict__ bias2,
    float* __restrict__ C0, float* __restrict__ C1, float* __restrict__ C2)
{
  __shared__ unsigned short Ah[128 * 32], Al[128 * 32];
  __shared__ unsigned short Bh[128 * 32], Bl[128 * 32];
  const int tid = threadIdx.x;
  const int wave = tid >> 6, lane = tid & 63;
  const int wr = wave >> 1, wc = wave & 1;

  const int lid = blockIdx.y * (4 * NW) + blockIdx.x;
  const int swz = (lid & 7) * (64 * NW) + (lid >> 3);
  const int wsel = swz >> 9;
  const int r9 = swz & 511;
  const int row0 = (r9 >> 2) * 128, col0 = (r9 & 3) * 128;

  const unsigned short* BhiT = (NW == 1 || wsel == 0) ? B0h : (wsel == 1) ? B1h : B2h;
  const unsigned short* BloT = (NW == 1 || wsel == 0) ? B0l : (wsel == 1) ? B1l : B2l;
  const float* bias          = (NW == 1 || wsel == 0) ? bias0 : (wsel == 1) ? bias1 : bias2;
  float* C                   = (NW == 1 || wsel == 0) ? C0 : (wsel == 1) ? C1 : C2;

  const int lr = lane & 15, lk = lane >> 4;
  f32x4 acc[4][4] = {};

  const int sr = tid >> 2;
  const int schunk = (tid & 3) ^ ((sr >> 1) & 3);
  const unsigned int lds0 = (unsigned int)wave * 512;
  const size_t ga0 = (size_t)(row0 + sr) * DD + (schunk << 3);
  const size_t ga1 = ga0 + (size_t)64 * DD;
  const size_t gb0 = (size_t)(col0 + sr) * DD + (schunk << 3);
  const size_t gb1 = gb0 + (size_t)64 * DD;

  int aoff[4], boff[4];
#pragma unroll
  for (int m = 0; m < 4; ++m) {
    int row = wr * 64 + m * 16 + lr;
    aoff[m] = row * 32 + ((lk ^ ((row >> 1) & 3)) << 3);
  }
#pragma unroll
  for (int n = 0; n < 4; ++n) {
    int row = wc * 64 + n * 16 + lr;
    boff[n] = row * 32 + ((lk ^ ((row >> 1) & 3)) << 3);
  }

  for (int k0 = 0; k0 < DD; k0 += 32) {
    gload16(Ahi + ga0 + k0, Ah + lds0);
    gload16(Ahi + ga1 + k0, Ah + lds0 + 2048);
    gload16(Alo + ga0 + k0, Al + lds0);
    gload16(Alo + ga1 + k0, Al + lds0 + 2048);
    gload16(BhiT + gb0 + k0, Bh + lds0);
    gload16(BhiT + gb1 + k0, Bh + lds0 + 2048);
    gload16(BloT + gb0 + k0, Bl + lds0);
    gload16(BloT + gb1 + k0, Bl + lds0 + 2048);
    __syncthreads();

    bf16x8 a[8], b[8];
#pragma unroll
    for (int m = 0; m < 4; ++m) {
      a[m]     = *(const bf16x8*)(Ah + aoff[m]);
      a[m + 4] = *(const bf16x8*)(Al + aoff[m]);
    }
#pragma unroll
    for (int n = 0; n < 4; ++n) {
      b[n]     = *(const bf16x8*)(Bh + boff[n]);
      b[n + 4] = *(const bf16x8*)(Bl + boff[n]);
    }
#pragma unroll
    for (int m = 0; m < 4; ++m)
#pragma unroll
      for (int n = 0; n < 4; ++n) {
        f32x4 c = acc[m][n];
        c = __builtin_amdgcn_mfma_f32_16x16x32_bf16(a[m],     b[n],     c, 0, 0, 0);
        c = __builtin_amdgcn_mfma_f32_16x16x32_bf16(a[m],     b[n + 4], c, 0, 0, 0);
        c = __builtin_amdgcn_mfma_f32_16x16x32_bf16(a[m + 4], b[n],     c, 0, 0, 0);
        acc[m][n] = c;
      }
    __syncthreads();
  }

  float bcol[4];
#pragma unroll
  for (int n = 0; n < 4; ++n) bcol[n] = bias[col0 + wc * 64 + n * 16 + lr];
#pragma unroll
  for (int m = 0; m < 4; ++m)
#pragma unroll
    for (int j = 0; j < 4; ++j) {
      int r = row0 + wr * 64 + m * 16 + lk * 4 + j;
#pragma unroll
      for (int n = 0; n < 4; ++n)
        C[(size_t)r * DD + col0 + wc * 64 + n * 16 + lr] = acc[m][n][j] + bcol[n];
    }
}

// ---------------------------------------------------------------------------
// NEW R11: batched scores GEMM via bf16x3 MFMA. A = Qr planes, B = Kr planes
// (both [MROWS][512] bf16, rows grouped 256/batch). Same staging/fragment/
// MFMA structure as gemm3m; no bias; C = scores [b][p][q] f32 (ld 256).
// Grid (2,2,64) = 256 blocks; bijective XCD swizzle.
// ---------------------------------------------------------------------------
__global__ __launch_bounds__(256) void gemm3s(
    const unsigned short* __restrict__ Qhi, const unsigned short* __restrict__ Qlo,
    const unsigned short* __restrict__ Khi, const unsigned short* __restrict__ Klo,
    float* __restrict__ S)
{
  __shared__ unsigned short Ah[128 * 32], Al[128 * 32];
  __shared__ unsigned short Bh[128 * 32], Bl[128 * 32];
  const int tid = threadIdx.x;
  const int wave = tid >> 6, lane = tid & 63;
  const int wr = wave >> 1, wc = wave & 1;

  const int lid = blockIdx.z * 4 + blockIdx.y * 2 + blockIdx.x;  // 0..255
  const int swz = (lid & 7) * 32 + (lid >> 3);
  const int b = swz >> 2, t4 = swz & 3;
  const int prow0 = b * PB + (t4 >> 1) * 128;   // A rows (q_r side)
  const int qrow0 = b * PB + (t4 & 1) * 128;    // B rows (k_r side)

  const int lr = lane & 15, lk = lane >> 4;
  f32x4 acc[4][4] = {};

  const int sr = tid >> 2;
  const int schunk = (tid & 3) ^ ((sr >> 1) & 3);
  const unsigned int lds0 = (unsigned int)wave * 512;
  const size_t ga0 = (size_t)(prow0 + sr) * DD + (schunk << 3);
  const size_t ga1 = ga0 + (size_t)64 * DD;
  const size_t gb0 = (size_t)(qrow0 + sr) * DD + (schunk << 3);
  const size_t gb1 = gb0 + (size_t)64 * DD;

  int aoff[4], boff[4];
#pragma unroll
  for (int m = 0; m < 4; ++m) {
    int row = wr * 64 + m * 16 + lr;
    aoff[m] = row * 32 + ((lk ^ ((row >> 1) & 3)) << 3);
  }
#pragma unroll
  for (int n = 0; n < 4; ++n) {
    int row = wc * 64 + n * 16 + lr;
    boff[n] = row * 32 + ((lk ^ ((row >> 1) & 3)) << 3);
  }

  for (int k0 = 0; k0 < DD; k0 += 32) {
    gload16(Qhi + ga0 + k0, Ah + lds0);
    gload16(Qhi + ga1 + k0, Ah + lds0 + 2048);
    gload16(Qlo + ga0 + k0, Al + lds0);
    gload16(Qlo + ga1 + k0, Al + lds0 + 2048);
    gload16(Khi + gb0 + k0, Bh + lds0);
    gload16(Khi + gb1 + k0, Bh + lds0 + 2048);
    gload16(Klo + gb0 + k0, Bl + lds0);
    gload16(Klo + gb1 + k0, Bl + lds0 + 2048);
    __syncthreads();

    bf16x8 a[8], bb[8];
#pragma unroll
    for (int m = 0; m < 4; ++m) {
      a[m]     = *(const bf16x8*)(Ah + aoff[m]);
      a[m + 4] = *(const bf16x8*)(Al + aoff[m]);
    }
#pragma unroll
    for (int n = 0; n < 4; ++n) {
      bb[n]     = *(const bf16x8*)(Bh + boff[n]);
      bb[n + 4] = *(const bf16x8*)(Bl + boff[n]);
    }
#pragma unroll
    for (int m = 0; m < 4; ++m)
#pragma unroll
      for (int n = 0; n < 4; ++n) {
        f32x4 c = acc[m][n];
        c = __builtin_amdgcn_mfma_f32_16x16x32_bf16(a[m],     bb[n],     c, 0, 0, 0);
        c = __builtin_amdgcn_mfma_f32_16x16x32_bf16(a[m],     bb[n + 4], c, 0, 0, 0);
        c = __builtin_amdgcn_mfma_f32_16x16x32_bf16(a[m + 4], bb[n],     c, 0, 0, 0);
        acc[m][n] = c;
      }
    __syncthreads();
  }

  float* Sb = S + (size_t)b * PB * PB;
#pragma unroll
  for (int m = 0; m < 4; ++m)
#pragma unroll
    for (int j = 0; j < 4; ++j) {
      int lp = (t4 >> 1) * 128 + wr * 64 + m * 16 + lk * 4 + j;
#pragma unroll
      for (int n = 0; n < 4; ++n) {
        int lq = (t4 & 1) * 128 + wc * 64 + n * 16 + lr;
        Sb[(size_t)lp * PB + lq] = acc[m][n][j];
      }
    }
}

// ---------------------------------------------------------------------------
// NEW R11: l2-normalize rows (identical f32 arithmetic to the proven
// l2norm_rows) and emit bf16 hi/lo planes for the MFMA scores GEMM.
// ---------------------------------------------------------------------------
__global__ __launch_bounds__(256) void l2norm_split(
    const float* __restrict__ X, unsigned short* __restrict__ hi,
    unsigned short* __restrict__ lo)
{
  const int row = blockIdx.x * 4 + (threadIdx.x >> 6);
  const int lane = threadIdx.x & 63;
  const float* base = X + (size_t)row * DD + lane * 8;
  float4 u = *(const float4*)base;
  float4 w = *(const float4*)(base + 4);
  float s = u.x * u.x + u.y * u.y + u.z * u.z + u.w * u.w +
            w.x * w.x + w.y * w.y + w.z * w.z + w.w * w.w;
#pragma unroll
  for (int off = 1; off < 64; off <<= 1) s += __shfl_xor(s, off);
  float inv = 1.0f / sqrtf(s + 1e-12f);
  float v[8] = {u.x * inv, u.y * inv, u.z * inv, u.w * inv,
                w.x * inv, w.y * inv, w.z * inv, w.w * inv};
  us8 H, L;
#pragma unroll
  for (int j = 0; j < 8; ++j) {
    unsigned short h = f2b(v[j]);
    H[j] = h;
    L[j] = f2b(v[j] - b2f(h));
  }
  size_t o = (size_t)row * DD + lane * 8;
  *(us8*)(hi + o) = H;
  *(us8*)(lo + o) = L;
}

// ---------------------------------------------------------------------------
// topk — unchanged
// ---------------------------------------------------------------------------
__global__ __launch_bounds__(256) void topk_routes(
    const float* __restrict__ S, const float* __restrict__ pb,
    int* __restrict__ routes)
{
  const int row = blockIdx.x * 4 + (threadIdx.x >> 6);
  const int lane = threadIdx.x & 63;
  const int p = row & 255;
  const float* srow = S + (long)row * 256;
  float v[4];
  int id[4];
#pragma unroll
  for (int i = 0; i < 4; ++i) {
    int q = i * 64 + lane;
    float s = srow[q] + pb[p * 256 + q];
    if (q == p) s = -1e9f;
    v[i] = s;
    id[i] = q;
  }
  for (int t = 0; t < 8; ++t) {
    float bv = v[0]; int bi = id[0]; int bs = 0;
#pragma unroll
    for (int i = 1; i < 4; ++i)
      if (v[i] > bv || (v[i] == bv && id[i] < bi)) { bv = v[i]; bi = id[i]; bs = i; }
    float rv = bv; int ri = bi;
#pragma unroll
    for (int off = 1; off < 64; off <<= 1) {
      float ov = __shfl_xor(rv, off);
      int oi = __shfl_xor(ri, off);
      if (ov > rv || (ov == rv && oi < ri)) { rv = ov; ri = oi; }
    }
    if (bi == ri) v[bs] = -INFINITY;
    if (lane == 0) routes[row * 8 + t] = ri;
  }
}

// ---------------------------------------------------------------------------
// Gathered 8-key attention; emits ctx as bf16 hi/lo planes for gemm3m.
// ---------------------------------------------------------------------------
__global__ __launch_bounds__(512) void wormhole_attn(
    const float* __restrict__ qh, const float* __restrict__ kh,
    const float* __restrict__ vh, const int* __restrict__ routes,
    unsigned short* __restrict__ chi, unsigned short* __restrict__ clo)
{
  const int bp = blockIdx.x;
  const int b = bp >> 8;
  const int tid = threadIdx.x;
  __shared__ int rs[8];
  if (tid < 8) rs[tid] = routes[bp * 8 + tid];
  __syncthreads();

  const float q = qh[(long)bp * DD + tid];
  long rbase[8];
  float s[8];
#pragma unroll
  for (int k = 0; k < 8; ++k) {
    long roff = ((long)((b << 8) | rs[k])) * DD + tid;
    rbase[k] = roff;
    float t = q * kh[roff];
#pragma unroll
    for (int off = 1; off < 64; off <<= 1) t += __shfl_xor(t, off);
    s[k] = t * 0.125f;
  }
  float m = s[0];
#pragma unroll
  for (int k = 1; k < 8; ++k) m = fmaxf(m, s[k]);
  float e[8], sum = 0.f;
#pragma unroll
  for (int k = 0; k < 8; ++k) { e[k] = expf(s[k] - m); sum += e[k]; }
  float inv = 1.0f / sum;
  float c = 0.f;
#pragma unroll
  for (int k = 0; k < 8; ++k) c = fmaf(e[k] * inv, vh[rbase[k]], c);
  unsigned short h = f2b(c);
  chi[(size_t)bp * DD + tid] = h;
  clo[(size_t)bp * DD + tid] = f2b(c - b2f(h));
}

// ---------------------------------------------------------------------------
extern "C" void kernel_launch(void* const* d_in, const int* in_sizes, int n_in,
                              void* d_out, int out_size, void* d_ws, size_t ws_size,
                              hipStream_t stream)
{
  const float* x        = (const float*)d_in[0];
  const float* wq_r     = (const float*)d_in[1];
  const float* bq_r     = (const float*)d_in[2];
  const float* wk_r     = (const float*)d_in[3];
  const float* bk_r     = (const float*)d_in[4];
  const float* pos_bias = (const float*)d_in[5];
  const float* wq       = (const float*)d_in[6];
  const float* bq       = (const float*)d_in[7];
  const float* wk       = (const float*)d_in[8];
  const float* bk       = (const float*)d_in[9];
  const float* wv       = (const float*)d_in[10];
  const float* bv       = (const float*)d_in[11];
  const float* wo       = (const float*)d_in[12];
  const float* bo       = (const float*)d_in[13];

  char* w = (char*)d_ws;
  const size_t SLOT = (size_t)MROWS * DD * sizeof(float);   // 33.55 MB
  const size_t PL   = (size_t)DD * DD;                      // 262144 ushorts/plane

  // slot1: X planes -> later ctx planes
  unsigned short* Xhi = (unsigned short*)w;
  unsigned short* Xlo = (unsigned short*)(w + SLOT / 2);
  // slot2: q_r f32 -> Kr planes -> K heads
  float* P2 = (float*)(w + SLOT);
  // slot3: k_r f32 -> scores f32 -> V heads
  float* P3 = (float*)(w + 2 * SLOT);
  // slot4: Wr splits (2MB, dead after gemm3m<2>) -> Qr planes -> Q heads
  char* s4 = w + 3 * SLOT;
  unsigned short* Wqr_hi = (unsigned short*)s4;
  unsigned short* Wqr_lo = Wqr_hi + PL;
  unsigned short* Wkr_hi = Wqr_hi + 2 * PL;
  unsigned short* Wkr_lo = Wqr_hi + 3 * PL;
  unsigned short* Qr_hi = (unsigned short*)s4;
  unsigned short* Qr_lo = (unsigned short*)(s4 + SLOT / 2);
  unsigned short* Kr_hi = (unsigned short*)(w + SLOT);
  unsigned short* Kr_lo = (unsigned short*)(w + SLOT + SLOT / 2);
  float* Sc = P3;                         // scores (lower 16.8 MB of slot3)

  int* routes = (int*)(w + 4 * SLOT);
  unsigned short* Wp = (unsigned short*)(w + 4 * SLOT + (1 << 20));
  unsigned short* Wq_hi = Wp + 0 * PL, *Wq_lo = Wp + 1 * PL;
  unsigned short* Wk_hi = Wp + 2 * PL, *Wk_lo = Wp + 3 * PL;
  unsigned short* Wv_hi = Wp + 4 * PL, *Wv_lo = Wp + 5 * PL;
  unsigned short* Wo_hi = Wp + 6 * PL, *Wo_lo = Wp + 7 * PL;

  unsigned short* Chi = Xhi;   // ctx planes overwrite X (dead after qkv GEMM)
  unsigned short* Clo = Xlo;

  dim3 blk(256);
  dim3 gw(8, 8);
  dim3 g3r(8, 128);             // gemm3m<2>: routing projections
  dim3 g3a(12, 128);            // gemm3m<3>: q,k,v projections
  dim3 g3b(4, 128);             // gemm3m<1>: output projection
  dim3 g3s(2, 2, 64);           // gemm3s: scores

  // --- operand prep (bf16 hi/lo splits)
  split_x<<<4096, 256, 0, stream>>>(x, Xhi, Xlo);
  split_w<<<gw, 256, 0, stream>>>(wq_r, Wqr_hi, Wqr_lo);
  split_w<<<gw, 256, 0, stream>>>(wk_r, Wkr_hi, Wkr_lo);
  split_w<<<gw, 256, 0, stream>>>(wq, Wq_hi, Wq_lo);
  split_w<<<gw, 256, 0, stream>>>(wk, Wk_hi, Wk_lo);
  split_w<<<gw, 256, 0, stream>>>(wv, Wv_hi, Wv_lo);
  split_w<<<gw, 256, 0, stream>>>(wo, Wo_hi, Wo_lo);

  // --- routing projections (bf16x3 MFMA, R9-proven) -> q_r (P2), k_r (P3)
  gemm3m<2><<<g3r, blk, 0, stream>>>(Xhi, Xlo,
      Wqr_hi, Wqr_lo, Wkr_hi, Wkr_lo, Wkr_hi, Wkr_lo,
      bq_r, bk_r, bk_r, P2, P3, P3);

  // --- l2norm + split (pass1 overwrites Wr in slot4; pass2 overwrites slot2)
  l2norm_split<<<MROWS / 4, 256, 0, stream>>>(P2, Qr_hi, Qr_lo);
  l2norm_split<<<MROWS / 4, 256, 0, stream>>>(P3, Kr_hi, Kr_lo);

  // --- scores via bf16x3 MFMA (THE experiment); writes slot3 (k_r f32 dead)
  gemm3s<<<g3s, blk, 0, stream>>>(Qr_hi, Qr_lo, Kr_hi, Kr_lo, Sc);
  topk_routes<<<MROWS / 4, 256, 0, stream>>>(Sc, pos_bias, routes);

  // --- q,k,v head projections -> Q=slot4, K=slot2, V=slot3 (planes dead)
  gemm3m<3><<<g3a, blk, 0, stream>>>(Xhi, Xlo,
      Wq_hi, Wq_lo, Wk_hi, Wk_lo, Wv_hi, Wv_lo,
      bq, bk, bv, (float*)s4, P2, P3);

  // --- gathered attention (ctx planes -> slot1) + output projection
  wormhole_attn<<<MROWS, 512, 0, stream>>>((float*)s4, P2, P3, routes, Chi, Clo);
  gemm3m<1><<<g3b, blk, 0, stream>>>(Chi, Clo,
      Wo_hi, Wo_lo, Wo_hi, Wo_lo, Wo_hi, Wo_lo,
      bo, bo, bo, (float*)d_out, (float*)d_out, (float*)d_out);
}